// Round 1
// baseline (13763.000 us; speedup 1.0000x reference)
//
#include <hip/hip_runtime.h>
#include <stdint.h>
#include <math.h>

// Decoder: autoregressive GRU (B=128,H=512,T=256) -> LSTM (L=1024) -> FC (V=1024)
// fp32 I/O. Internal math fp32; GEMMs via MFMA 16x16x32 bf16 with split-bf16
// (hi/lo) weights AND activations, 3-pass MFMA.
//
// Round 5: the LSTM h-state broadcast (256 blocks x 640 KB/step of sc0sc1 LLC
// reads ~= 164 MB/step ~= 4.8 TB/s = the measured 34 us/step) is replaced by
// per-XCD L2 staging: each XCD's blocks cooperatively copy h (512 KB) from LLC
// into a per-XCD scratch (plain stores -> dirty in that XCD's L2), then all
// blocks read it with sc0-only loads (L1-bypass, L2-hit). LLC h-traffic drops
// 32x (164 MB -> ~5 MB/step). XCD identity via s_getreg(HW_REG_XCC_ID) +
// one-time registration, so correctness holds under any block->XCD assignment.

typedef unsigned short u16;
typedef unsigned int u32;
typedef __attribute__((ext_vector_type(8))) short short8;   // 8 bf16 = 4 VGPR
typedef __attribute__((ext_vector_type(4))) float float4_;  // MFMA acc

#define MFMA(a, b, c) __builtin_amdgcn_mfma_f32_16x16x32_bf16((a), (b), (c), 0, 0, 0)

// System-coherent (LLC) 16B load, bypasses L1+L2; usable only after an owning wait.
#define SC_LOAD(dst, ptr) \
  asm volatile("global_load_dwordx4 %0, %1, off sc0 sc1" : "=v"(dst) : "v"(ptr) : "memory")
// Agent-lite 16B load: bypasses L1, reads this XCD's L2 (sees same-XCD dirty lines).
#define SC0_LOAD(dst, ptr) \
  asm volatile("global_load_dwordx4 %0, %1, off sc0" : "=v"(dst) : "v"(ptr) : "memory")
// s_waitcnt that also "owns" 8 loaded regs so consumers can't be hoisted above it.
#define WAIT8(n, a0,a1,a2,a3,a4,a5,a6,a7) \
  asm volatile("s_waitcnt vmcnt(" #n ")" \
    : "+v"(a0),"+v"(a1),"+v"(a2),"+v"(a3),"+v"(a4),"+v"(a5),"+v"(a6),"+v"(a7) :: "memory")
// wait binding a single short8
#define WAIT1(a0) \
  asm volatile("s_waitcnt vmcnt(0)" : "+v"(a0) :: "memory")
// Coherent 2B store (write-through to LLC, complete when vmcnt retires).
#define SC_STORE16(ptr, val) \
  asm volatile("global_store_short %0, %1, off sc0 sc1" :: "v"(ptr), "v"((u32)(val)) : "memory")

__device__ __forceinline__ float bf2f(u16 u) {
  union { u32 i; float f; } v; v.i = ((u32)u) << 16; return v.f;
}
__device__ __forceinline__ u16 f2bf(float f) {
  union { float f; u32 i; } v; v.f = f;
  u32 x = v.i;
  return (u16)((x + 0x7fffu + ((x >> 16) & 1u)) >> 16);  // RNE, finite inputs only
}
__device__ __forceinline__ void split2(float w, u16& h, u16& l) {
  h = f2bf(w); l = f2bf(w - bf2f(h));
}
__device__ __forceinline__ float sigm(float x) { return 1.0f / (1.0f + expf(-x)); }

__device__ __forceinline__ void frag_from_f32(const float* p, short8& hi, short8& lo) {
  short8 h, l;
#pragma unroll
  for (int j = 0; j < 8; ++j) {
    u16 a, b; split2(p[j], a, b);
    h[j] = (short)a; l[j] = (short)b;
  }
  hi = h; lo = l;
}

// Fence-free grid barrier: payload is sc-coherent at vmcnt retirement, so we
// drain vmcnt in every lane, block-barrier, then one relaxed arrive + spin.
__device__ __forceinline__ void grid_barrier(u32* bar, u32 gen, u32 nblk) {
  asm volatile("s_waitcnt vmcnt(0)" ::: "memory");
  __syncthreads();
  if (threadIdx.x == 0) {
    atomicAdd(bar, 1u);                      // device-scope, coherence point
    const u32 target = gen * nblk;
    while (__hip_atomic_load(bar, __ATOMIC_RELAXED, __HIP_MEMORY_SCOPE_AGENT) < target)
      __builtin_amdgcn_s_sleep(2);
  }
  __syncthreads();
}

// ---------------------------------------------------------------------------
// Kernel 1: persistent GRU chain. 128 blocks x 256 threads. Unchanged (control).
// ---------------------------------------------------------------------------
__global__ __launch_bounds__(256)
void gru_chain(const float* __restrict__ z,
               const float* __restrict__ Wih, const float* __restrict__ Whh,
               const float* __restrict__ bih, const float* __restrict__ bhh,
               u16* outu, u16* __restrict__ xpp, u32* bar) {
  __shared__ __align__(16) u16 wh_lds[48 * 520];
  __shared__ __align__(16) u16 wl_lds[48 * 520];
  __shared__ float blds[32];

  const int tid = threadIdx.x;
  const int wg = blockIdx.x;
  const int grp = wg & 63;
  const int mhalf = wg >> 6;
  const int jb = grp * 8;

  for (int idx = tid; idx < 48 * 512; idx += 256) {
    int row = idx >> 9, k = idx & 511;
    int t3 = row >> 4, n = row & 15;
    int grow = t3 * 512 + jb + (n & 7);
    float w = ((n < 8) ? Wih : Whh)[(size_t)grow * 512 + k];
    u16 h, l; split2(w, h, l);
    wh_lds[row * 520 + k] = h;
    wl_lds[row * 520 + k] = l;
  }
  if (tid < 8) {
    blds[tid]      = bih[jb + tid] + bhh[jb + tid];
    blds[8 + tid]  = bih[512 + jb + tid] + bhh[512 + jb + tid];
    blds[16 + tid] = bih[1024 + jb + tid];
    blds[24 + tid] = bhh[1024 + jb + tid];
  }
  __syncthreads();

  const int lane = tid & 63, wv = tid >> 6;
  const int n16 = lane & 15, q = lane >> 4;
  const int j8 = n16 & 7;
  const int mrow = mhalf * 64 + wv * 16 + n16;
  const int orow0 = mhalf * 64 + wv * 16 + q * 4;
  const bool act = (n16 < 8);
  const int col = jb + j8;
  const int qo = q * 8;

  float x_own[4];

  // ---- step 1: x1 = GRU(x=0, h=z); A = z hi/lo (normal cached loads) ----
  {
    float4_ acc0 = {0.f, 0.f, 0.f, 0.f}, acc1 = acc0, acc2 = acc0;
    for (int ki = 0; ki < 16; ++ki) {
      const int ko = ki * 32 + qo;
      short8 ah, al;
      frag_from_f32(z + (size_t)mrow * 512 + ko, ah, al);
      short8 b0h = *(const short8*)(wh_lds + (0 * 16 + n16) * 520 + ko);
      short8 b1h = *(const short8*)(wh_lds + (1 * 16 + n16) * 520 + ko);
      short8 b2h = *(const short8*)(wh_lds + (2 * 16 + n16) * 520 + ko);
      short8 b0l = *(const short8*)(wl_lds + (0 * 16 + n16) * 520 + ko);
      short8 b1l = *(const short8*)(wl_lds + (1 * 16 + n16) * 520 + ko);
      short8 b2l = *(const short8*)(wl_lds + (2 * 16 + n16) * 520 + ko);
      acc0 = MFMA(ah, b0h, acc0); acc0 = MFMA(al, b0h, acc0); acc0 = MFMA(ah, b0l, acc0);
      acc1 = MFMA(ah, b1h, acc1); acc1 = MFMA(al, b1h, acc1); acc1 = MFMA(ah, b1l, acc1);
      acc2 = MFMA(ah, b2h, acc2); acc2 = MFMA(al, b2h, acc2); acc2 = MFMA(ah, b2l, acc2);
    }
    for (int reg = 0; reg < 4; ++reg) {
      float pr = __shfl_xor(acc0[reg], 8);
      float pz = __shfl_xor(acc1[reg], 8);
      float pn = __shfl_xor(acc2[reg], 8);
      float r  = sigm(pr + blds[j8]);
      float zg = sigm(pz + blds[8 + j8]);
      float nn = tanhf(blds[16 + j8] + r * (pn + blds[24 + j8]));
      float hv = act ? z[(size_t)(orow0 + reg) * 512 + col] : 0.f;
      float xn = (1.f - zg) * nn + zg * hv;
      x_own[reg] = xn;
      if (act) {
        size_t po = (size_t)(orow0 + reg) * 512 + col;
        u16 h, l; split2(xn, h, l);
        SC_STORE16(xpp + (size_t)2 * 65536 + po, h);   // slot 1 hi
        SC_STORE16(xpp + (size_t)3 * 65536 + po, l);   // slot 1 lo
        float rl = fmaxf(xn, 0.f);
        u16 rh, rlo; split2(rl, rh, rlo);
        size_t so = ((size_t)(orow0 + reg) * 256 + 1) * 2048;
        outu[so + col] = rh;
        outu[so + 512 + col] = rlo;
      }
    }
  }
  grid_barrier(bar, 1, 128);

  // ---- steps 2..255: A = x_{t-1} hi/lo via sc loads (issue-all, wait-all) ----
  for (int t = 2; t < 256; ++t) {
    const int sr = (t - 1) & 1, sw = t & 1;
    const u16* xh = xpp + (size_t)(sr * 2 + 0) * 65536 + (size_t)mrow * 512;
    const u16* xl = xpp + (size_t)(sr * 2 + 1) * 65536 + (size_t)mrow * 512;
    short8 bufh[16], bufl[16];
#pragma unroll
    for (int ki = 0; ki < 16; ++ki) {
      SC_LOAD(bufh[ki], xh + ki * 32 + qo);
      SC_LOAD(bufl[ki], xl + ki * 32 + qo);
    }
    WAIT8(0, bufh[0], bufh[1], bufh[2], bufh[3], bufh[4], bufh[5], bufh[6], bufh[7]);
    WAIT8(0, bufh[8], bufh[9], bufh[10], bufh[11], bufh[12], bufh[13], bufh[14], bufh[15]);
    WAIT8(0, bufl[0], bufl[1], bufl[2], bufl[3], bufl[4], bufl[5], bufl[6], bufl[7]);
    WAIT8(0, bufl[8], bufl[9], bufl[10], bufl[11], bufl[12], bufl[13], bufl[14], bufl[15]);

    float4_ acc0 = {0.f, 0.f, 0.f, 0.f}, acc1 = acc0, acc2 = acc0;
#pragma unroll
    for (int ki = 0; ki < 16; ++ki) {
      const int ko = ki * 32 + qo;
      short8 b0h = *(const short8*)(wh_lds + (0 * 16 + n16) * 520 + ko);
      short8 b1h = *(const short8*)(wh_lds + (1 * 16 + n16) * 520 + ko);
      short8 b2h = *(const short8*)(wh_lds + (2 * 16 + n16) * 520 + ko);
      short8 b0l = *(const short8*)(wl_lds + (0 * 16 + n16) * 520 + ko);
      short8 b1l = *(const short8*)(wl_lds + (1 * 16 + n16) * 520 + ko);
      short8 b2l = *(const short8*)(wl_lds + (2 * 16 + n16) * 520 + ko);
      acc0 = MFMA(bufh[ki], b0h, acc0); acc0 = MFMA(bufl[ki], b0h, acc0); acc0 = MFMA(bufh[ki], b0l, acc0);
      acc1 = MFMA(bufh[ki], b1h, acc1); acc1 = MFMA(bufl[ki], b1h, acc1); acc1 = MFMA(bufh[ki], b1l, acc1);
      acc2 = MFMA(bufh[ki], b2h, acc2); acc2 = MFMA(bufl[ki], b2h, acc2); acc2 = MFMA(bufh[ki], b2l, acc2);
    }
    for (int reg = 0; reg < 4; ++reg) {
      float ar = acc0[reg], az = acc1[reg], an = acc2[reg];
      float pr = __shfl_xor(ar, 8), pz = __shfl_xor(az, 8), pn = __shfl_xor(an, 8);
      float r  = sigm(ar + pr + blds[j8]);
      float zg = sigm(az + pz + blds[8 + j8]);
      float nn = tanhf(an + blds[16 + j8] + r * (pn + blds[24 + j8]));
      float xn = (1.f - zg) * nn + zg * x_own[reg];
      x_own[reg] = xn;
      if (act) {
        size_t po = (size_t)(orow0 + reg) * 512 + col;
        u16 h, l; split2(xn, h, l);
        SC_STORE16(xpp + (size_t)(sw * 2 + 0) * 65536 + po, h);
        SC_STORE16(xpp + (size_t)(sw * 2 + 1) * 65536 + po, l);
        float rl = fmaxf(xn, 0.f);
        u16 rh, rlo; split2(rl, rh, rlo);
        size_t so = ((size_t)(orow0 + reg) * 256 + (size_t)t) * 2048;
        outu[so + col] = rh;
        outu[so + 512 + col] = rlo;
      }
    }
    if (t < 255) grid_barrier(bar, t, 128);
  }
}

// ---------------------------------------------------------------------------
// Kernel 2: persistent LSTM chain with fused FC. 256 blocks x 512 threads.
// Round 5: per-XCD L2 staging of h; recurrent + FC h reads via sc0 (L2-hit)
// from the XCD-local scratch instead of sc0sc1 (LLC) broadcast.
// ---------------------------------------------------------------------------
__global__ __launch_bounds__(512)
void lstm_fc_chain(const float* __restrict__ Wih, const float* __restrict__ Whh,
                   const float* __restrict__ bih, const float* __restrict__ bhh,
                   const float* __restrict__ fcW, const float* __restrict__ fcb,
                   u16* __restrict__ hpp, u16* outu, float* outf, u32* bar,
                   u32* xcnt, u32* xbar, u16* scr) {
  __shared__ __align__(16) u16 whh_hi[16 * 1032];
  __shared__ __align__(16) u16 whh_lo[16 * 1032];
  __shared__ __align__(16) u16 wih_hi[16 * 520];
  __shared__ __align__(16) u16 wih_lo[16 * 520];
  __shared__ float glds[128][17];
  __shared__ float pglds[2][16][4][16];
  __shared__ float bclds[16];
  __shared__ float fclds[16];
  __shared__ u32 sh_rank, sh_nx;

  const int tid = threadIdx.x;
  const int s = blockIdx.x;
  const int colbase = s * 4;
  const int vt = s & 63, bq = s >> 6;
  const int vbase = vt * 16;

  // --- XCD identity + one-time registration (robust to any block->XCD map) ---
  u32 xcd_raw;
  asm volatile("s_getreg_b32 %0, hwreg(HW_REG_XCC_ID, 0, 32)" : "=s"(xcd_raw));
  const u32 xcd = xcd_raw & 7u;
  if (tid == 0) sh_rank = atomicAdd(&xcnt[xcd], 1u);

  for (int idx = tid; idx < 16 * 1024; idx += 512) {
    int row = idx >> 10, k = idx & 1023;
    int gate = row >> 2, cc = row & 3;
    float w = Whh[(size_t)(gate * 1024 + colbase + cc) * 1024 + k];
    u16 h, l; split2(w, h, l);
    whh_hi[row * 1032 + k] = h;
    whh_lo[row * 1032 + k] = l;
  }
  for (int idx = tid; idx < 16 * 512; idx += 512) {
    int row = idx >> 9, k = idx & 511;
    int gate = row >> 2, cc = row & 3;
    float w = Wih[(size_t)(gate * 1024 + colbase + cc) * 512 + k];
    u16 h, l; split2(w, h, l);
    wih_hi[row * 520 + k] = h;
    wih_lo[row * 520 + k] = l;
  }
  if (tid < 16) {
    int gate = tid >> 2, cc = tid & 3;
    int wcol = gate * 1024 + colbase + cc;
    bclds[tid] = bih[wcol] + bhh[wcol];
    fclds[tid] = fcb[vbase + tid];
  }
  __syncthreads();

  const int lane = tid & 63, wv = tid >> 6;
  const int n16 = lane & 15, q = lane >> 4;
  const int qo = q * 8;
  const int arow = wv * 16 + n16;
  const int myrow = tid >> 2, mycol = tid & 3;
  const int fmt = wv & 1, fkq = wv >> 1;
  const int frow = bq * 32 + fmt * 16 + n16;
  const int fkbase = fkq * 256;

  u16* const scrx = scr + (size_t)xcd * 262144;   // this XCD's h mirror (hi|lo planes)
  u32* const xbarx = xbar + (size_t)xcd * 32;     // this XCD's barrier counter (128B apart)

  short8 brh[8], brl[8];
  for (int i = 0; i < 8; ++i)
    frag_from_f32(fcW + (size_t)(vbase + n16) * 1024 + fkbase + i * 32 + qo,
                  brh[i], brl[i]);

  float c = 0.f;

  // t = 0: preacts are just biases
  {
    float pi = bclds[mycol], pg = bclds[8 + mycol], po = bclds[12 + mycol];
    c = sigm(pi) * tanhf(pg);
    float h = sigm(po) * tanhf(c);
    size_t off = (size_t)myrow * 1024 + colbase + mycol;
    u16 hh, hl; split2(h, hh, hl);
    SC_STORE16(hpp + off, hh);
    SC_STORE16(hpp + 131072 + off, hl);
  }
  grid_barrier(bar, 1, 256);

  // registration is complete once every block passed the barrier above
  if (tid == 0)
    sh_nx = __hip_atomic_load(&xcnt[xcd], __ATOMIC_RELAXED, __HIP_MEMORY_SCOPE_AGENT);
  __syncthreads();
  const u32 rank = sh_rank, nx = sh_nx;

  for (int t = 1; t < 256; ++t) {
    const int sr = (t - 1) & 1, sw = t & 1;
    float4_ acc = {0.f, 0.f, 0.f, 0.f};

    // ---- (1) issue per-XCD staging loads: hpp slot sr (512 KB) -> regs ----
    // Expected nx=32 => exactly 2 vectors/thread; generic tail keeps it correct
    // for any nx. LLC latency hides under the input-part GEMM below.
    const u16* ssrc = hpp + (size_t)sr * 262144;
    const u32 stride = nx * 512u;
    const u32 v0 = rank * 512u + (u32)tid;
    const u32 v1 = v0 + stride;
    const bool h0 = v0 < 32768u, h1 = v1 < 32768u;
    short8 sa, sb;
    if (h0) SC_LOAD(sa, ssrc + (size_t)v0 * 8);
    if (h1) SC_LOAD(sb, ssrc + (size_t)v1 * 8);

    // ---- (2) input part, K=512: seq planes from outu (L2-warm, cached) ----
    {
      const u16* sq = outu + ((size_t)arow * 256 + t) * 2048;
      for (int ki = 0; ki < 16; ++ki) {
        const int ko = ki * 32 + qo;
        short8 shh = *(const short8*)(sq + ko);
        short8 sll = *(const short8*)(sq + 512 + ko);
        short8 bh = *(const short8*)(wih_hi + n16 * 520 + ko);
        short8 bl = *(const short8*)(wih_lo + n16 * 520 + ko);
        acc = MFMA(shh, bh, acc); acc = MFMA(sll, bh, acc); acc = MFMA(shh, bl, acc);
      }
    }

    // ---- (3) write scratch (plain stores -> dirty in this XCD's L2) ----
    if (h0) { WAIT1(sa); *(short8*)(scrx + (size_t)v0 * 8) = sa; }
    if (h1) { WAIT1(sb); *(short8*)(scrx + (size_t)v1 * 8) = sb; }
    for (u32 v = v1 + stride; v < 32768u; v += stride) {   // tail (nx<16 only)
      short8 tcv; SC_LOAD(tcv, ssrc + (size_t)v * 8);
      WAIT1(tcv);
      *(short8*)(scrx + (size_t)v * 8) = tcv;
    }

    // ---- (4) per-XCD barrier: scratch fully resident in local L2 ----
    asm volatile("s_waitcnt vmcnt(0)" ::: "memory");
    __syncthreads();
    if (tid == 0) {
      atomicAdd(xbarx, 1u);
      const u32 target = (u32)t * nx;
      while (__hip_atomic_load(xbarx, __ATOMIC_RELAXED, __HIP_MEMORY_SCOPE_AGENT) < target)
        __builtin_amdgcn_s_sleep(1);
    }
    __syncthreads();

    // ---- (5) recurrent part, K=1024, from XCD-local scratch via sc0 (L2) ----
    {
      const u16* ph = scrx + (size_t)arow * 1024;
      const u16* pl = ph + 131072;
      short8 hb[2][8], lb[2][8];
#pragma unroll
      for (int j = 0; j < 8; ++j) {
        SC0_LOAD(hb[0][j], ph + j * 32 + qo);
        SC0_LOAD(lb[0][j], pl + j * 32 + qo);
      }
#pragma unroll
      for (int ch = 0; ch < 4; ++ch) {
        const int cur = ch & 1, nxt = cur ^ 1;
        if (ch < 3) {
#pragma unroll
          for (int j = 0; j < 8; ++j) {
            SC0_LOAD(hb[nxt][j], ph + ((ch + 1) * 8 + j) * 32 + qo);
            SC0_LOAD(lb[nxt][j], pl + ((ch + 1) * 8 + j) * 32 + qo);
          }
          WAIT8(16, hb[cur][0], hb[cur][1], hb[cur][2], hb[cur][3],
                    hb[cur][4], hb[cur][5], hb[cur][6], hb[cur][7]);
          WAIT8(16, lb[cur][0], lb[cur][1], lb[cur][2], lb[cur][3],
                    lb[cur][4], lb[cur][5], lb[cur][6], lb[cur][7]);
        } else {
          WAIT8(0, hb[cur][0], hb[cur][1], hb[cur][2], hb[cur][3],
                   hb[cur][4], hb[cur][5], hb[cur][6], hb[cur][7]);
          WAIT8(0, lb[cur][0], lb[cur][1], lb[cur][2], lb[cur][3],
                   lb[cur][4], lb[cur][5], lb[cur][6], lb[cur][7]);
        }
#pragma unroll
        for (int j = 0; j < 8; ++j) {
          const int ko = (ch * 8 + j) * 32 + qo;
          short8 bh = *(const short8*)(whh_hi + n16 * 1032 + ko);
          short8 bl = *(const short8*)(whh_lo + n16 * 1032 + ko);
          acc = MFMA(hb[cur][j], bh, acc);
          acc = MFMA(lb[cur][j], bh, acc);
          acc = MFMA(hb[cur][j], bl, acc);
        }
      }
    }
    for (int reg = 0; reg < 4; ++reg)
      glds[wv * 16 + q * 4 + reg][n16] = acc[reg];
    __syncthreads();
    {
      float pi = glds[myrow][mycol]      + bclds[mycol];
      float pf = glds[myrow][4 + mycol]  + bclds[4 + mycol];
      float pg = glds[myrow][8 + mycol]  + bclds[8 + mycol];
      float po = glds[myrow][12 + mycol] + bclds[12 + mycol];
      c = sigm(pf) * c + sigm(pi) * tanhf(pg);
      float h = sigm(po) * tanhf(c);
      size_t off = (size_t)myrow * 1024 + colbase + mycol;
      u16 hh, hl; split2(h, hh, hl);
      SC_STORE16(hpp + (size_t)(sw * 2 + 0) * 131072 + off, hh);
      SC_STORE16(hpp + (size_t)(sw * 2 + 1) * 131072 + off, hl);
    }

    // fused FC: logits_{t-1} from h_{t-1}, also from XCD-local scratch (sc0)
    {
      const u16* fh = scrx + (size_t)frow * 1024 + fkbase;
      const u16* fl = fh + 131072;
      short8 fhb[8], flb[8];
#pragma unroll
      for (int i = 0; i < 8; ++i) {
        SC0_LOAD(fhb[i], fh + i * 32 + qo);
        SC0_LOAD(flb[i], fl + i * 32 + qo);
      }
      WAIT8(0, fhb[0], fhb[1], fhb[2], fhb[3], fhb[4], fhb[5], fhb[6], fhb[7]);
      WAIT8(0, flb[0], flb[1], flb[2], flb[3], flb[4], flb[5], flb[6], flb[7]);
      float4_ lacc = {0.f, 0.f, 0.f, 0.f};
#pragma unroll
      for (int i = 0; i < 8; ++i) {
        lacc = MFMA(fhb[i], brh[i], lacc);
        lacc = MFMA(flb[i], brh[i], lacc);
        lacc = MFMA(fhb[i], brl[i], lacc);
      }
      for (int reg = 0; reg < 4; ++reg)
        pglds[fmt][q * 4 + reg][fkq][n16] = lacc[reg];
      __syncthreads();
      int trow = tid >> 4, tcol = tid & 15;
      float lsum = pglds[trow >> 4][trow & 15][0][tcol] + pglds[trow >> 4][trow & 15][1][tcol] +
                   pglds[trow >> 4][trow & 15][2][tcol] + pglds[trow >> 4][trow & 15][3][tcol] +
                   fclds[tcol];
      outf[((size_t)(bq * 32 + trow) * 256 + (t - 1)) * 1024 + vbase + tcol] = lsum;
    }
    grid_barrier(bar, t + 1, 256);
  }

  // epilogue: logits_255 from h_255 (slot 1; read from LLC -- scratch holds h_254)
  {
    const u16* fh = hpp + (size_t)(1 * 2 + 0) * 131072 + (size_t)frow * 1024 + fkbase;
    const u16* fl = hpp + (size_t)(1 * 2 + 1) * 131072 + (size_t)frow * 1024 + fkbase;
    short8 fhb[8], flb[8];
#pragma unroll
    for (int i = 0; i < 8; ++i) {
      SC_LOAD(fhb[i], fh + i * 32 + qo);
      SC_LOAD(flb[i], fl + i * 32 + qo);
    }
    WAIT8(0, fhb[0], fhb[1], fhb[2], fhb[3], fhb[4], fhb[5], fhb[6], fhb[7]);
    WAIT8(0, flb[0], flb[1], flb[2], flb[3], flb[4], flb[5], flb[6], flb[7]);
    float4_ lacc = {0.f, 0.f, 0.f, 0.f};
#pragma unroll
    for (int i = 0; i < 8; ++i) {
      lacc = MFMA(fhb[i], brh[i], lacc);
      lacc = MFMA(flb[i], brh[i], lacc);
      lacc = MFMA(fhb[i], brl[i], lacc);
    }
    for (int reg = 0; reg < 4; ++reg)
      pglds[fmt][q * 4 + reg][fkq][n16] = lacc[reg];
    __syncthreads();
    int trow = tid >> 4, tcol = tid & 15;
    float lsum = pglds[trow >> 4][trow & 15][0][tcol] + pglds[trow >> 4][trow & 15][1][tcol] +
                 pglds[trow >> 4][trow & 15][2][tcol] + pglds[trow >> 4][trow & 15][3][tcol] +
                 fclds[tcol];
    outf[((size_t)(bq * 32 + trow) * 256 + 255) * 1024 + vbase + tcol] = lsum;
  }
}

// ---------------------------------------------------------------------------
extern "C" void kernel_launch(void* const* d_in, const int* in_sizes, int n_in,
                              void* d_out, int out_size, void* d_ws, size_t ws_size,
                              hipStream_t stream) {
  (void)in_sizes; (void)n_in; (void)out_size;
  const float* z    = (const float*)d_in[0];
  const float* gWih = (const float*)d_in[2];
  const float* gWhh = (const float*)d_in[3];
  const float* gbih = (const float*)d_in[4];
  const float* gbhh = (const float*)d_in[5];
  const float* lWih = (const float*)d_in[6];
  const float* lWhh = (const float*)d_in[7];
  const float* lbih = (const float*)d_in[8];
  const float* lbhh = (const float*)d_in[9];
  const float* fcW  = (const float*)d_in[10];
  const float* fcb  = (const float*)d_in[11];

  // 4 KB counters | xpp 512 KB | hpp 1 MB | per-XCD scratch 4 MB
  const size_t ws_need = 4096 + 524288 + 1048576 + 4194304;
  if (ws_size < ws_need) return;

  char* w = (char*)d_ws;
  u32* barg = (u32*)(w + 0);
  u32* barl = (u32*)(w + 256);
  u32* xcnt = (u32*)(w + 512);             // [8] per-XCD block count
  u32* xbar = (u32*)(w + 1024);            // [8] per-XCD barrier, 128 B apart
  u16* xpp = (u16*)(w + 4096);             // [2 slot][hi/lo][128*512]  = 512 KB
  u16* hpp = (u16*)(w + 4096 + 524288);    // [2 slot][hi/lo][128*1024] = 1 MB
  u16* scr = (u16*)(w + 4096 + 524288 + 1048576);  // [8 xcd][hi|lo][128*1024] = 4 MB

  hipMemsetAsync(d_ws, 0, 4096, stream);   // zero all barrier/registration counters

  gru_chain<<<128, 256, 0, stream>>>(z, gWih, gWhh, gbih, gbhh,
                                     (u16*)d_out, xpp, barg);
  lstm_fc_chain<<<256, 512, 0, stream>>>(lWih, lWhh, lbih, lbhh, fcW, fcb,
                                         hpp, (u16*)d_out, (float*)d_out, barl,
                                         xcnt, xbar, scr);
}

// Round 2
// 11340.578 us; speedup vs baseline: 1.2136x; 1.2136x over previous
//
#include <hip/hip_runtime.h>
#include <stdint.h>
#include <math.h>

// Decoder: autoregressive GRU (B=128,H=512,T=256) -> LSTM (L=1024) -> FC (V=1024)
// fp32 I/O. Internal math fp32; GEMMs via MFMA 16x16x32 bf16 with split-bf16
// (hi/lo) weights AND activations, 3-pass MFMA.
//
// Round 6: revert round-5's per-XCD L2 staging (sc0-only loads missed L2 ->
// FETCH_SIZE 0.8->10.6 GB, regression). New mechanism: RING mode. Each step
// writes recurrent state to a FRESH slot (256-slot ring, one per timestep), so
// consumers can use PLAIN CACHED loads -- per-XCD L2 dedupes the broadcast
// (LLC read drops 256x to one 512KB fill per XCD per step), with zero stale-
// line hazard because ring addresses are never reused within a dispatch
// (dispatch-boundary invalidation covers bench-iteration reuse; the seq/outu
// path already proves plain-load broadcast works cross-dispatch). Producers
// still store sc0 sc1 (write-through to LLC, drained before the grid-barrier
// arrive). Tiered by ws_size: both rings -> LSTM ring only -> round-4 2-slot
// sc0sc1 fallback (bit-identical to the 11.07 ms baseline).

typedef unsigned short u16;
typedef unsigned int u32;
typedef __attribute__((ext_vector_type(8))) short short8;   // 8 bf16 = 4 VGPR
typedef __attribute__((ext_vector_type(4))) float float4_;  // MFMA acc

#define MFMA(a, b, c) __builtin_amdgcn_mfma_f32_16x16x32_bf16((a), (b), (c), 0, 0, 0)

// System-coherent (LLC) 16B load, bypasses L1+L2; usable only after an owning wait.
#define SC_LOAD(dst, ptr) \
  asm volatile("global_load_dwordx4 %0, %1, off sc0 sc1" : "=v"(dst) : "v"(ptr) : "memory")
// s_waitcnt that also "owns" 8 loaded regs so consumers can't be hoisted above it.
#define WAIT8(n, a0,a1,a2,a3,a4,a5,a6,a7) \
  asm volatile("s_waitcnt vmcnt(" #n ")" \
    : "+v"(a0),"+v"(a1),"+v"(a2),"+v"(a3),"+v"(a4),"+v"(a5),"+v"(a6),"+v"(a7) :: "memory")
// Coherent 2B store (write-through to LLC, complete when vmcnt retires).
#define SC_STORE16(ptr, val) \
  asm volatile("global_store_short %0, %1, off sc0 sc1" :: "v"(ptr), "v"((u32)(val)) : "memory")

__device__ __forceinline__ float bf2f(u16 u) {
  union { u32 i; float f; } v; v.i = ((u32)u) << 16; return v.f;
}
__device__ __forceinline__ u16 f2bf(float f) {
  union { float f; u32 i; } v; v.f = f;
  u32 x = v.i;
  return (u16)((x + 0x7fffu + ((x >> 16) & 1u)) >> 16);  // RNE, finite inputs only
}
__device__ __forceinline__ void split2(float w, u16& h, u16& l) {
  h = f2bf(w); l = f2bf(w - bf2f(h));
}
__device__ __forceinline__ float sigm(float x) { return 1.0f / (1.0f + expf(-x)); }

__device__ __forceinline__ void frag_from_f32(const float* p, short8& hi, short8& lo) {
  short8 h, l;
#pragma unroll
  for (int j = 0; j < 8; ++j) {
    u16 a, b; split2(p[j], a, b);
    h[j] = (short)a; l[j] = (short)b;
  }
  hi = h; lo = l;
}

// Fence-free grid barrier: payload is sc-coherent at vmcnt retirement, so we
// drain vmcnt in every lane, block-barrier, then one relaxed arrive + spin.
__device__ __forceinline__ void grid_barrier(u32* bar, u32 gen, u32 nblk) {
  asm volatile("s_waitcnt vmcnt(0)" ::: "memory");
  __syncthreads();
  if (threadIdx.x == 0) {
    atomicAdd(bar, 1u);                      // device-scope, coherence point
    const u32 target = gen * nblk;
    while (__hip_atomic_load(bar, __ATOMIC_RELAXED, __HIP_MEMORY_SCOPE_AGENT) < target)
      __builtin_amdgcn_s_sleep(2);
  }
  __syncthreads();
}

// ---------------------------------------------------------------------------
// Kernel 1: persistent GRU chain. 128 blocks x 256 threads.
// RING=0: exact round-4 behavior (2-slot sc0sc1). RING=1: 256-slot ring,
// plain cached consumer loads (per-XCD L2 dedup).
// Slot layout (both modes): xpp + slot*131072 + plane*65536, plane in {hi,lo}.
// ---------------------------------------------------------------------------
template<bool RING>
__global__ __launch_bounds__(256)
void gru_chain(const float* __restrict__ z,
               const float* __restrict__ Wih, const float* __restrict__ Whh,
               const float* __restrict__ bih, const float* __restrict__ bhh,
               u16* outu, u16* __restrict__ xpp, u32* bar) {
  __shared__ __align__(16) u16 wh_lds[48 * 520];
  __shared__ __align__(16) u16 wl_lds[48 * 520];
  __shared__ float blds[32];

  const int tid = threadIdx.x;
  const int wg = blockIdx.x;
  const int grp = wg & 63;
  const int mhalf = wg >> 6;
  const int jb = grp * 8;

  for (int idx = tid; idx < 48 * 512; idx += 256) {
    int row = idx >> 9, k = idx & 511;
    int t3 = row >> 4, n = row & 15;
    int grow = t3 * 512 + jb + (n & 7);
    float w = ((n < 8) ? Wih : Whh)[(size_t)grow * 512 + k];
    u16 h, l; split2(w, h, l);
    wh_lds[row * 520 + k] = h;
    wl_lds[row * 520 + k] = l;
  }
  if (tid < 8) {
    blds[tid]      = bih[jb + tid] + bhh[jb + tid];
    blds[8 + tid]  = bih[512 + jb + tid] + bhh[512 + jb + tid];
    blds[16 + tid] = bih[1024 + jb + tid];
    blds[24 + tid] = bhh[1024 + jb + tid];
  }
  __syncthreads();

  const int lane = tid & 63, wv = tid >> 6;
  const int n16 = lane & 15, q = lane >> 4;
  const int j8 = n16 & 7;
  const int mrow = mhalf * 64 + wv * 16 + n16;
  const int orow0 = mhalf * 64 + wv * 16 + q * 4;
  const bool act = (n16 < 8);
  const int col = jb + j8;
  const int qo = q * 8;

  float x_own[4];

  // ---- step 1: x1 = GRU(x=0, h=z); A = z hi/lo (normal cached loads) ----
  {
    float4_ acc0 = {0.f, 0.f, 0.f, 0.f}, acc1 = acc0, acc2 = acc0;
    for (int ki = 0; ki < 16; ++ki) {
      const int ko = ki * 32 + qo;
      short8 ah, al;
      frag_from_f32(z + (size_t)mrow * 512 + ko, ah, al);
      short8 b0h = *(const short8*)(wh_lds + (0 * 16 + n16) * 520 + ko);
      short8 b1h = *(const short8*)(wh_lds + (1 * 16 + n16) * 520 + ko);
      short8 b2h = *(const short8*)(wh_lds + (2 * 16 + n16) * 520 + ko);
      short8 b0l = *(const short8*)(wl_lds + (0 * 16 + n16) * 520 + ko);
      short8 b1l = *(const short8*)(wl_lds + (1 * 16 + n16) * 520 + ko);
      short8 b2l = *(const short8*)(wl_lds + (2 * 16 + n16) * 520 + ko);
      acc0 = MFMA(ah, b0h, acc0); acc0 = MFMA(al, b0h, acc0); acc0 = MFMA(ah, b0l, acc0);
      acc1 = MFMA(ah, b1h, acc1); acc1 = MFMA(al, b1h, acc1); acc1 = MFMA(ah, b1l, acc1);
      acc2 = MFMA(ah, b2h, acc2); acc2 = MFMA(al, b2h, acc2); acc2 = MFMA(ah, b2l, acc2);
    }
    for (int reg = 0; reg < 4; ++reg) {
      float pr = __shfl_xor(acc0[reg], 8);
      float pz = __shfl_xor(acc1[reg], 8);
      float pn = __shfl_xor(acc2[reg], 8);
      float r  = sigm(pr + blds[j8]);
      float zg = sigm(pz + blds[8 + j8]);
      float nn = tanhf(blds[16 + j8] + r * (pn + blds[24 + j8]));
      float hv = act ? z[(size_t)(orow0 + reg) * 512 + col] : 0.f;
      float xn = (1.f - zg) * nn + zg * hv;
      x_own[reg] = xn;
      if (act) {
        size_t po = (size_t)(orow0 + reg) * 512 + col;
        u16 h, l; split2(xn, h, l);
        SC_STORE16(xpp + (size_t)1 * 131072 + po, h);           // slot 1 hi
        SC_STORE16(xpp + (size_t)1 * 131072 + 65536 + po, l);   // slot 1 lo
        float rl = fmaxf(xn, 0.f);
        u16 rh, rlo; split2(rl, rh, rlo);
        size_t so = ((size_t)(orow0 + reg) * 256 + 1) * 2048;
        outu[so + col] = rh;
        outu[so + 512 + col] = rlo;
      }
    }
  }
  grid_barrier(bar, 1, 128);

  // ---- steps 2..255: A = x_{t-1} hi/lo ----
  for (int t = 2; t < 256; ++t) {
    const size_t sr = RING ? (size_t)(t - 1) : (size_t)((t - 1) & 1);
    const size_t sw = RING ? (size_t)t       : (size_t)(t & 1);
    const u16* xh = xpp + sr * 131072 + (size_t)mrow * 512;
    const u16* xl = xh + 65536;
    short8 bufh[16], bufl[16];
    if constexpr (RING) {
#pragma unroll
      for (int ki = 0; ki < 16; ++ki) {
        bufh[ki] = *(const short8*)(xh + ki * 32 + qo);
        bufl[ki] = *(const short8*)(xl + ki * 32 + qo);
      }
    } else {
#pragma unroll
      for (int ki = 0; ki < 16; ++ki) {
        SC_LOAD(bufh[ki], xh + ki * 32 + qo);
        SC_LOAD(bufl[ki], xl + ki * 32 + qo);
      }
      WAIT8(0, bufh[0], bufh[1], bufh[2], bufh[3], bufh[4], bufh[5], bufh[6], bufh[7]);
      WAIT8(0, bufh[8], bufh[9], bufh[10], bufh[11], bufh[12], bufh[13], bufh[14], bufh[15]);
      WAIT8(0, bufl[0], bufl[1], bufl[2], bufl[3], bufl[4], bufl[5], bufl[6], bufl[7]);
      WAIT8(0, bufl[8], bufl[9], bufl[10], bufl[11], bufl[12], bufl[13], bufl[14], bufl[15]);
    }

    float4_ acc0 = {0.f, 0.f, 0.f, 0.f}, acc1 = acc0, acc2 = acc0;
#pragma unroll
    for (int ki = 0; ki < 16; ++ki) {
      const int ko = ki * 32 + qo;
      short8 b0h = *(const short8*)(wh_lds + (0 * 16 + n16) * 520 + ko);
      short8 b1h = *(const short8*)(wh_lds + (1 * 16 + n16) * 520 + ko);
      short8 b2h = *(const short8*)(wh_lds + (2 * 16 + n16) * 520 + ko);
      short8 b0l = *(const short8*)(wl_lds + (0 * 16 + n16) * 520 + ko);
      short8 b1l = *(const short8*)(wl_lds + (1 * 16 + n16) * 520 + ko);
      short8 b2l = *(const short8*)(wl_lds + (2 * 16 + n16) * 520 + ko);
      acc0 = MFMA(bufh[ki], b0h, acc0); acc0 = MFMA(bufl[ki], b0h, acc0); acc0 = MFMA(bufh[ki], b0l, acc0);
      acc1 = MFMA(bufh[ki], b1h, acc1); acc1 = MFMA(bufl[ki], b1h, acc1); acc1 = MFMA(bufh[ki], b1l, acc1);
      acc2 = MFMA(bufh[ki], b2h, acc2); acc2 = MFMA(bufl[ki], b2h, acc2); acc2 = MFMA(bufh[ki], b2l, acc2);
    }
    for (int reg = 0; reg < 4; ++reg) {
      float ar = acc0[reg], az = acc1[reg], an = acc2[reg];
      float pr = __shfl_xor(ar, 8), pz = __shfl_xor(az, 8), pn = __shfl_xor(an, 8);
      float r  = sigm(ar + pr + blds[j8]);
      float zg = sigm(az + pz + blds[8 + j8]);
      float nn = tanhf(an + blds[16 + j8] + r * (pn + blds[24 + j8]));
      float xn = (1.f - zg) * nn + zg * x_own[reg];
      x_own[reg] = xn;
      if (act) {
        size_t po = (size_t)(orow0 + reg) * 512 + col;
        u16 h, l; split2(xn, h, l);
        SC_STORE16(xpp + sw * 131072 + po, h);
        SC_STORE16(xpp + sw * 131072 + 65536 + po, l);
        float rl = fmaxf(xn, 0.f);
        u16 rh, rlo; split2(rl, rh, rlo);
        size_t so = ((size_t)(orow0 + reg) * 256 + (size_t)t) * 2048;
        outu[so + col] = rh;
        outu[so + 512 + col] = rlo;
      }
    }
    if (t < 255) grid_barrier(bar, t, 128);
  }
}

// ---------------------------------------------------------------------------
// Kernel 2: persistent LSTM chain with fused FC. 256 blocks x 512 threads.
// RING=0: exact round-4 behavior. RING=1: 256-slot h ring, plain cached
// consumer loads.
// Slot layout (both modes): hpp + slot*262144 + plane*131072.
// ---------------------------------------------------------------------------
template<bool RING>
__global__ __launch_bounds__(512)
void lstm_fc_chain(const float* __restrict__ Wih, const float* __restrict__ Whh,
                   const float* __restrict__ bih, const float* __restrict__ bhh,
                   const float* __restrict__ fcW, const float* __restrict__ fcb,
                   u16* __restrict__ hpp, u16* outu, float* outf, u32* bar) {
  __shared__ __align__(16) u16 whh_hi[16 * 1032];
  __shared__ __align__(16) u16 whh_lo[16 * 1032];
  __shared__ __align__(16) u16 wih_hi[16 * 520];
  __shared__ __align__(16) u16 wih_lo[16 * 520];
  __shared__ float glds[128][17];
  __shared__ float pglds[2][16][4][16];
  __shared__ float bclds[16];
  __shared__ float fclds[16];

  const int tid = threadIdx.x;
  const int s = blockIdx.x;
  const int colbase = s * 4;
  const int vt = s & 63, bq = s >> 6;
  const int vbase = vt * 16;

  for (int idx = tid; idx < 16 * 1024; idx += 512) {
    int row = idx >> 10, k = idx & 1023;
    int gate = row >> 2, cc = row & 3;
    float w = Whh[(size_t)(gate * 1024 + colbase + cc) * 1024 + k];
    u16 h, l; split2(w, h, l);
    whh_hi[row * 1032 + k] = h;
    whh_lo[row * 1032 + k] = l;
  }
  for (int idx = tid; idx < 16 * 512; idx += 512) {
    int row = idx >> 9, k = idx & 511;
    int gate = row >> 2, cc = row & 3;
    float w = Wih[(size_t)(gate * 1024 + colbase + cc) * 512 + k];
    u16 h, l; split2(w, h, l);
    wih_hi[row * 520 + k] = h;
    wih_lo[row * 520 + k] = l;
  }
  if (tid < 16) {
    int gate = tid >> 2, cc = tid & 3;
    int wcol = gate * 1024 + colbase + cc;
    bclds[tid] = bih[wcol] + bhh[wcol];
    fclds[tid] = fcb[vbase + tid];
  }
  __syncthreads();

  const int lane = tid & 63, wv = tid >> 6;
  const int n16 = lane & 15, q = lane >> 4;
  const int qo = q * 8;
  const int arow = wv * 16 + n16;
  const int myrow = tid >> 2, mycol = tid & 3;
  const int fmt = wv & 1, fkq = wv >> 1;
  const int frow = bq * 32 + fmt * 16 + n16;
  const int fkbase = fkq * 256;

  short8 brh[8], brl[8];
  for (int i = 0; i < 8; ++i)
    frag_from_f32(fcW + (size_t)(vbase + n16) * 1024 + fkbase + i * 32 + qo,
                  brh[i], brl[i]);

  float c = 0.f;

  // t = 0: preacts are just biases; write h_0 into slot 0
  {
    float pi = bclds[mycol], pg = bclds[8 + mycol], po = bclds[12 + mycol];
    c = sigm(pi) * tanhf(pg);
    float h = sigm(po) * tanhf(c);
    size_t off = (size_t)myrow * 1024 + colbase + mycol;
    u16 hh, hl; split2(h, hh, hl);
    SC_STORE16(hpp + off, hh);
    SC_STORE16(hpp + 131072 + off, hl);
  }
  grid_barrier(bar, 1, 256);

  for (int t = 1; t < 256; ++t) {
    const size_t sr = RING ? (size_t)(t - 1) : (size_t)((t - 1) & 1);
    const size_t sw = RING ? (size_t)t       : (size_t)(t & 1);
    const u16* ph = hpp + sr * 262144 + (size_t)arow * 1024;
    const u16* pl = ph + 131072;
    float4_ acc = {0.f, 0.f, 0.f, 0.f};

    // recurrent part, K=1024: 4 chunks of 8 ki, double-buffered loads
    {
      short8 hb[2][8], lb[2][8];
      if constexpr (RING) {
#pragma unroll
        for (int j = 0; j < 8; ++j) {
          hb[0][j] = *(const short8*)(ph + j * 32 + qo);
          lb[0][j] = *(const short8*)(pl + j * 32 + qo);
        }
#pragma unroll
        for (int ch = 0; ch < 4; ++ch) {
          const int cur = ch & 1, nxt = cur ^ 1;
          if (ch < 3) {
#pragma unroll
            for (int j = 0; j < 8; ++j) {
              hb[nxt][j] = *(const short8*)(ph + ((ch + 1) * 8 + j) * 32 + qo);
              lb[nxt][j] = *(const short8*)(pl + ((ch + 1) * 8 + j) * 32 + qo);
            }
          }
#pragma unroll
          for (int j = 0; j < 8; ++j) {
            const int ko = (ch * 8 + j) * 32 + qo;
            short8 bh = *(const short8*)(whh_hi + n16 * 1032 + ko);
            short8 bl = *(const short8*)(whh_lo + n16 * 1032 + ko);
            acc = MFMA(hb[cur][j], bh, acc);
            acc = MFMA(lb[cur][j], bh, acc);
            acc = MFMA(hb[cur][j], bl, acc);
          }
        }
      } else {
#pragma unroll
        for (int j = 0; j < 8; ++j) {
          SC_LOAD(hb[0][j], ph + j * 32 + qo);
          SC_LOAD(lb[0][j], pl + j * 32 + qo);
        }
#pragma unroll
        for (int ch = 0; ch < 4; ++ch) {
          const int cur = ch & 1, nxt = cur ^ 1;
          if (ch < 3) {
#pragma unroll
            for (int j = 0; j < 8; ++j) {
              SC_LOAD(hb[nxt][j], ph + ((ch + 1) * 8 + j) * 32 + qo);
              SC_LOAD(lb[nxt][j], pl + ((ch + 1) * 8 + j) * 32 + qo);
            }
            WAIT8(16, hb[cur][0], hb[cur][1], hb[cur][2], hb[cur][3],
                      hb[cur][4], hb[cur][5], hb[cur][6], hb[cur][7]);
            WAIT8(16, lb[cur][0], lb[cur][1], lb[cur][2], lb[cur][3],
                      lb[cur][4], lb[cur][5], lb[cur][6], lb[cur][7]);
          } else {
            WAIT8(0, hb[cur][0], hb[cur][1], hb[cur][2], hb[cur][3],
                     hb[cur][4], hb[cur][5], hb[cur][6], hb[cur][7]);
            WAIT8(0, lb[cur][0], lb[cur][1], lb[cur][2], lb[cur][3],
                     lb[cur][4], lb[cur][5], lb[cur][6], lb[cur][7]);
          }
#pragma unroll
          for (int j = 0; j < 8; ++j) {
            const int ko = (ch * 8 + j) * 32 + qo;
            short8 bh = *(const short8*)(whh_hi + n16 * 1032 + ko);
            short8 bl = *(const short8*)(whh_lo + n16 * 1032 + ko);
            acc = MFMA(hb[cur][j], bh, acc);
            acc = MFMA(lb[cur][j], bh, acc);
            acc = MFMA(hb[cur][j], bl, acc);
          }
        }
      }
    }
    // input part, K=512: seq planes from outu (normal cached loads, L2-warm)
    {
      const u16* sq = outu + ((size_t)arow * 256 + t) * 2048;
      for (int ki = 0; ki < 16; ++ki) {
        const int ko = ki * 32 + qo;
        short8 sh = *(const short8*)(sq + ko);
        short8 sl = *(const short8*)(sq + 512 + ko);
        short8 bh = *(const short8*)(wih_hi + n16 * 520 + ko);
        short8 bl = *(const short8*)(wih_lo + n16 * 520 + ko);
        acc = MFMA(sh, bh, acc); acc = MFMA(sl, bh, acc); acc = MFMA(sh, bl, acc);
      }
    }
    for (int reg = 0; reg < 4; ++reg)
      glds[wv * 16 + q * 4 + reg][n16] = acc[reg];
    __syncthreads();
    {
      float pi = glds[myrow][mycol]      + bclds[mycol];
      float pf = glds[myrow][4 + mycol]  + bclds[4 + mycol];
      float pg = glds[myrow][8 + mycol]  + bclds[8 + mycol];
      float po = glds[myrow][12 + mycol] + bclds[12 + mycol];
      c = sigm(pf) * c + sigm(pi) * tanhf(pg);
      float h = sigm(po) * tanhf(c);
      size_t off = (size_t)myrow * 1024 + colbase + mycol;
      u16 hh, hl; split2(h, hh, hl);
      SC_STORE16(hpp + sw * 262144 + off, hh);
      SC_STORE16(hpp + sw * 262144 + 131072 + off, hl);
    }

    // fused FC: logits_{t-1} from h_{t-1} (slot sr)
    {
      const u16* fh = hpp + sr * 262144 + (size_t)frow * 1024 + fkbase;
      const u16* fl = fh + 131072;
      short8 fhb[8], flb[8];
      if constexpr (RING) {
#pragma unroll
        for (int i = 0; i < 8; ++i) {
          fhb[i] = *(const short8*)(fh + i * 32 + qo);
          flb[i] = *(const short8*)(fl + i * 32 + qo);
        }
      } else {
#pragma unroll
        for (int i = 0; i < 8; ++i) {
          SC_LOAD(fhb[i], fh + i * 32 + qo);
          SC_LOAD(flb[i], fl + i * 32 + qo);
        }
        WAIT8(0, fhb[0], fhb[1], fhb[2], fhb[3], fhb[4], fhb[5], fhb[6], fhb[7]);
        WAIT8(0, flb[0], flb[1], flb[2], flb[3], flb[4], flb[5], flb[6], flb[7]);
      }
      float4_ lacc = {0.f, 0.f, 0.f, 0.f};
#pragma unroll
      for (int i = 0; i < 8; ++i) {
        lacc = MFMA(fhb[i], brh[i], lacc);
        lacc = MFMA(flb[i], brh[i], lacc);
        lacc = MFMA(fhb[i], brl[i], lacc);
      }
      for (int reg = 0; reg < 4; ++reg)
        pglds[fmt][q * 4 + reg][fkq][n16] = lacc[reg];
      __syncthreads();
      int trow = tid >> 4, tcol = tid & 15;
      float lsum = pglds[trow >> 4][trow & 15][0][tcol] + pglds[trow >> 4][trow & 15][1][tcol] +
                   pglds[trow >> 4][trow & 15][2][tcol] + pglds[trow >> 4][trow & 15][3][tcol] +
                   fclds[tcol];
      outf[((size_t)(bq * 32 + trow) * 256 + (t - 1)) * 1024 + vbase + tcol] = lsum;
    }
    grid_barrier(bar, t + 1, 256);
  }

  // epilogue: logits_255 from h_255 (ring: slot 255; 2-slot: slot 1)
  {
    const size_t sl = RING ? (size_t)255 : (size_t)1;
    const u16* fh = hpp + sl * 262144 + (size_t)frow * 1024 + fkbase;
    const u16* fl = fh + 131072;
    short8 fhb[8], flb[8];
    if constexpr (RING) {
#pragma unroll
      for (int i = 0; i < 8; ++i) {
        fhb[i] = *(const short8*)(fh + i * 32 + qo);
        flb[i] = *(const short8*)(fl + i * 32 + qo);
      }
    } else {
#pragma unroll
      for (int i = 0; i < 8; ++i) {
        SC_LOAD(fhb[i], fh + i * 32 + qo);
        SC_LOAD(flb[i], fl + i * 32 + qo);
      }
      WAIT8(0, fhb[0], fhb[1], fhb[2], fhb[3], fhb[4], fhb[5], fhb[6], fhb[7]);
      WAIT8(0, flb[0], flb[1], flb[2], flb[3], flb[4], flb[5], flb[6], flb[7]);
    }
    float4_ lacc = {0.f, 0.f, 0.f, 0.f};
#pragma unroll
    for (int i = 0; i < 8; ++i) {
      lacc = MFMA(fhb[i], brh[i], lacc);
      lacc = MFMA(flb[i], brh[i], lacc);
      lacc = MFMA(fhb[i], brl[i], lacc);
    }
    for (int reg = 0; reg < 4; ++reg)
      pglds[fmt][q * 4 + reg][fkq][n16] = lacc[reg];
    __syncthreads();
    int trow = tid >> 4, tcol = tid & 15;
    float lsum = pglds[trow >> 4][trow & 15][0][tcol] + pglds[trow >> 4][trow & 15][1][tcol] +
                 pglds[trow >> 4][trow & 15][2][tcol] + pglds[trow >> 4][trow & 15][3][tcol] +
                 fclds[tcol];
    outf[((size_t)(bq * 32 + trow) * 256 + 255) * 1024 + vbase + tcol] = lsum;
  }
}

// ---------------------------------------------------------------------------
extern "C" void kernel_launch(void* const* d_in, const int* in_sizes, int n_in,
                              void* d_out, int out_size, void* d_ws, size_t ws_size,
                              hipStream_t stream) {
  (void)in_sizes; (void)n_in; (void)out_size;
  const float* z    = (const float*)d_in[0];
  const float* gWih = (const float*)d_in[2];
  const float* gWhh = (const float*)d_in[3];
  const float* gbih = (const float*)d_in[4];
  const float* gbhh = (const float*)d_in[5];
  const float* lWih = (const float*)d_in[6];
  const float* lWhh = (const float*)d_in[7];
  const float* lbih = (const float*)d_in[8];
  const float* lbhh = (const float*)d_in[9];
  const float* fcW  = (const float*)d_in[10];
  const float* fcb  = (const float*)d_in[11];

  // Ring sizes (bytes): x slot = 256 KB, h slot = 512 KB, 256 slots each.
  const size_t XRING = 256ull * 262144ull;   //  67.1 MB
  const size_t HRING = 256ull * 524288ull;   // 134.2 MB
  const size_t X2    = 524288ull;            // 2-slot x
  const size_t H2    = 1048576ull;           // 2-slot h

  const size_t need2 = 4096 + XRING + HRING; // both rings
  const size_t need1 = 4096 + X2 + HRING;    // lstm ring only
  const size_t need0 = 4096 + X2 + H2;       // round-4 fallback

  char* w = (char*)d_ws;
  u32* barg = (u32*)(w + 0);
  u32* barl = (u32*)(w + 256);

  bool ringG = false, ringL = false;
  u16 *xpp, *hpp;
  if (ws_size >= need2) {
    ringG = true; ringL = true;
    xpp = (u16*)(w + 4096);
    hpp = (u16*)(w + 4096 + XRING);
  } else if (ws_size >= need1) {
    ringL = true;
    xpp = (u16*)(w + 4096);
    hpp = (u16*)(w + 4096 + X2);
  } else if (ws_size >= need0) {
    xpp = (u16*)(w + 4096);
    hpp = (u16*)(w + 4096 + X2);
  } else {
    return;
  }

  hipMemsetAsync(d_ws, 0, 4096, stream);   // zero barrier counters

  if (ringG)
    gru_chain<true><<<128, 256, 0, stream>>>(z, gWih, gWhh, gbih, gbhh,
                                             (u16*)d_out, xpp, barg);
  else
    gru_chain<false><<<128, 256, 0, stream>>>(z, gWih, gWhh, gbih, gbhh,
                                              (u16*)d_out, xpp, barg);

  if (ringL)
    lstm_fc_chain<true><<<256, 512, 0, stream>>>(lWih, lWhh, lbih, lbhh, fcW, fcb,
                                                 hpp, (u16*)d_out, (float*)d_out, barl);
  else
    lstm_fc_chain<false><<<256, 512, 0, stream>>>(lWih, lWhh, lbih, lbhh, fcW, fcb,
                                                  hpp, (u16*)d_out, (float*)d_out, barl);
}

// Round 3
// 10880.294 us; speedup vs baseline: 1.2649x; 1.0423x over previous
//
#include <hip/hip_runtime.h>
#include <stdint.h>
#include <math.h>

// Decoder: autoregressive GRU (B=128,H=512,T=256) -> LSTM (L=1024) -> FC (V=1024)
// fp32 I/O. Internal math fp32; GEMMs via MFMA 16x16x32 bf16 with split-bf16
// (hi/lo) weights AND activations, 3-pass MFMA.
//
// Round 7: round-6's 256-slot ring never ran (ws_size < 134.7 MB -> fallback;
// counters bit-matched round 0). Same dedup mechanism, bounded footprint:
// C-slot ring (C = 8..128, tiered by ws_size) + a system-scope ACQUIRE fence
// (invalidate-only buffer_inv, no writeback) once every C steps. Every slot
// reuse window (t, t+C] contains exactly one fence, so plain cached consumer
// loads can never observe a stale line; per-XCD L2 dedupes the h/x broadcast
// (LLC reads drop 256->8 fills/step). Producers keep sc0sc1 write-through
// stores drained before the grid-barrier arrive. Smallest ring tier (CG=0,
// CL=8) needs 4.72 MB < the 5.77 MB floor proven in round 5, so the ring is
// guaranteed to engage; exact round-0 kernel remains as final fallback.

typedef unsigned short u16;
typedef unsigned int u32;
typedef __attribute__((ext_vector_type(8))) short short8;   // 8 bf16 = 4 VGPR
typedef __attribute__((ext_vector_type(4))) float float4_;  // MFMA acc

#define MFMA(a, b, c) __builtin_amdgcn_mfma_f32_16x16x32_bf16((a), (b), (c), 0, 0, 0)

// System-coherent (LLC) 16B load, bypasses L1+L2; usable only after an owning wait.
#define SC_LOAD(dst, ptr) \
  asm volatile("global_load_dwordx4 %0, %1, off sc0 sc1" : "=v"(dst) : "v"(ptr) : "memory")
// s_waitcnt that also "owns" 8 loaded regs so consumers can't be hoisted above it.
#define WAIT8(n, a0,a1,a2,a3,a4,a5,a6,a7) \
  asm volatile("s_waitcnt vmcnt(" #n ")" \
    : "+v"(a0),"+v"(a1),"+v"(a2),"+v"(a3),"+v"(a4),"+v"(a5),"+v"(a6),"+v"(a7) :: "memory")
// Coherent 2B store (write-through to LLC, complete when vmcnt retires).
#define SC_STORE16(ptr, val) \
  asm volatile("global_store_short %0, %1, off sc0 sc1" :: "v"(ptr), "v"((u32)(val)) : "memory")

__device__ __forceinline__ float bf2f(u16 u) {
  union { u32 i; float f; } v; v.i = ((u32)u) << 16; return v.f;
}
__device__ __forceinline__ u16 f2bf(float f) {
  union { float f; u32 i; } v; v.f = f;
  u32 x = v.i;
  return (u16)((x + 0x7fffu + ((x >> 16) & 1u)) >> 16);  // RNE, finite inputs only
}
__device__ __forceinline__ void split2(float w, u16& h, u16& l) {
  h = f2bf(w); l = f2bf(w - bf2f(h));
}
__device__ __forceinline__ float sigm(float x) { return 1.0f / (1.0f + expf(-x)); }

__device__ __forceinline__ void frag_from_f32(const float* p, short8& hi, short8& lo) {
  short8 h, l;
#pragma unroll
  for (int j = 0; j < 8; ++j) {
    u16 a, b; split2(p[j], a, b);
    h[j] = (short)a; l[j] = (short)b;
  }
  hi = h; lo = l;
}

// System-scope acquire: s_waitcnt + buffer_inv sc0 sc1 (invalidate-only; dirty
// lines preserved -- this is the sequence the compiler emits for every
// system-scope atomic acquire, so it cannot be data-destroying).
__device__ __forceinline__ void cache_acquire() {
  __builtin_amdgcn_fence(__ATOMIC_ACQUIRE, "");
}

// Fence-free grid barrier: payload is sc-coherent at vmcnt retirement, so we
// drain vmcnt in every lane, block-barrier, then one relaxed arrive + spin.
__device__ __forceinline__ void grid_barrier(u32* bar, u32 gen, u32 nblk) {
  asm volatile("s_waitcnt vmcnt(0)" ::: "memory");
  __syncthreads();
  if (threadIdx.x == 0) {
    atomicAdd(bar, 1u);                      // device-scope, coherence point
    const u32 target = gen * nblk;
    while (__hip_atomic_load(bar, __ATOMIC_RELAXED, __HIP_MEMORY_SCOPE_AGENT) < target)
      __builtin_amdgcn_s_sleep(2);
  }
  __syncthreads();
}

// ---------------------------------------------------------------------------
// Kernel 1: persistent GRU chain. 128 blocks x 256 threads.
// C==0: exact round-4 behavior (2-slot sc0sc1). C>0 (power of 2): C-slot ring,
// plain cached consumer loads + acquire fence every C steps.
// Slot layout (both modes): xpp + slot*131072 + plane*65536, plane in {hi,lo}.
// ---------------------------------------------------------------------------
template<int C>
__global__ __launch_bounds__(256)
void gru_chain(const float* __restrict__ z,
               const float* __restrict__ Wih, const float* __restrict__ Whh,
               const float* __restrict__ bih, const float* __restrict__ bhh,
               u16* outu, u16* __restrict__ xpp, u32* bar) {
  __shared__ __align__(16) u16 wh_lds[48 * 520];
  __shared__ __align__(16) u16 wl_lds[48 * 520];
  __shared__ float blds[32];

  const int tid = threadIdx.x;
  const int wg = blockIdx.x;
  const int grp = wg & 63;
  const int mhalf = wg >> 6;
  const int jb = grp * 8;

  for (int idx = tid; idx < 48 * 512; idx += 256) {
    int row = idx >> 9, k = idx & 511;
    int t3 = row >> 4, n = row & 15;
    int grow = t3 * 512 + jb + (n & 7);
    float w = ((n < 8) ? Wih : Whh)[(size_t)grow * 512 + k];
    u16 h, l; split2(w, h, l);
    wh_lds[row * 520 + k] = h;
    wl_lds[row * 520 + k] = l;
  }
  if (tid < 8) {
    blds[tid]      = bih[jb + tid] + bhh[jb + tid];
    blds[8 + tid]  = bih[512 + jb + tid] + bhh[512 + jb + tid];
    blds[16 + tid] = bih[1024 + jb + tid];
    blds[24 + tid] = bhh[1024 + jb + tid];
  }
  __syncthreads();

  const int lane = tid & 63, wv = tid >> 6;
  const int n16 = lane & 15, q = lane >> 4;
  const int j8 = n16 & 7;
  const int mrow = mhalf * 64 + wv * 16 + n16;
  const int orow0 = mhalf * 64 + wv * 16 + q * 4;
  const bool act = (n16 < 8);
  const int col = jb + j8;
  const int qo = q * 8;

  float x_own[4];

  // ---- step 1: x1 = GRU(x=0, h=z); A = z hi/lo (normal cached loads) ----
  {
    float4_ acc0 = {0.f, 0.f, 0.f, 0.f}, acc1 = acc0, acc2 = acc0;
    for (int ki = 0; ki < 16; ++ki) {
      const int ko = ki * 32 + qo;
      short8 ah, al;
      frag_from_f32(z + (size_t)mrow * 512 + ko, ah, al);
      short8 b0h = *(const short8*)(wh_lds + (0 * 16 + n16) * 520 + ko);
      short8 b1h = *(const short8*)(wh_lds + (1 * 16 + n16) * 520 + ko);
      short8 b2h = *(const short8*)(wh_lds + (2 * 16 + n16) * 520 + ko);
      short8 b0l = *(const short8*)(wl_lds + (0 * 16 + n16) * 520 + ko);
      short8 b1l = *(const short8*)(wl_lds + (1 * 16 + n16) * 520 + ko);
      short8 b2l = *(const short8*)(wl_lds + (2 * 16 + n16) * 520 + ko);
      acc0 = MFMA(ah, b0h, acc0); acc0 = MFMA(al, b0h, acc0); acc0 = MFMA(ah, b0l, acc0);
      acc1 = MFMA(ah, b1h, acc1); acc1 = MFMA(al, b1h, acc1); acc1 = MFMA(ah, b1l, acc1);
      acc2 = MFMA(ah, b2h, acc2); acc2 = MFMA(al, b2h, acc2); acc2 = MFMA(ah, b2l, acc2);
    }
    for (int reg = 0; reg < 4; ++reg) {
      float pr = __shfl_xor(acc0[reg], 8);
      float pz = __shfl_xor(acc1[reg], 8);
      float pn = __shfl_xor(acc2[reg], 8);
      float r  = sigm(pr + blds[j8]);
      float zg = sigm(pz + blds[8 + j8]);
      float nn = tanhf(blds[16 + j8] + r * (pn + blds[24 + j8]));
      float hv = act ? z[(size_t)(orow0 + reg) * 512 + col] : 0.f;
      float xn = (1.f - zg) * nn + zg * hv;
      x_own[reg] = xn;
      if (act) {
        size_t po = (size_t)(orow0 + reg) * 512 + col;
        u16 h, l; split2(xn, h, l);
        SC_STORE16(xpp + (size_t)1 * 131072 + po, h);           // slot 1 hi
        SC_STORE16(xpp + (size_t)1 * 131072 + 65536 + po, l);   // slot 1 lo
        float rl = fmaxf(xn, 0.f);
        u16 rh, rlo; split2(rl, rh, rlo);
        size_t so = ((size_t)(orow0 + reg) * 256 + 1) * 2048;
        outu[so + col] = rh;
        outu[so + 512 + col] = rlo;
      }
    }
  }
  grid_barrier(bar, 1, 128);

  // ---- steps 2..255: A = x_{t-1} hi/lo ----
  for (int t = 2; t < 256; ++t) {
    if constexpr (C > 0) {
      if ((t & (C - 1)) == 0) cache_acquire();   // kill stale ring lines
    }
    const size_t sr = (C > 0) ? (size_t)((t - 1) & (C - 1)) : (size_t)((t - 1) & 1);
    const size_t sw = (C > 0) ? (size_t)(t & (C - 1))       : (size_t)(t & 1);
    const u16* xh = xpp + sr * 131072 + (size_t)mrow * 512;
    const u16* xl = xh + 65536;
    short8 bufh[16], bufl[16];
    if constexpr (C > 0) {
#pragma unroll
      for (int ki = 0; ki < 16; ++ki) {
        bufh[ki] = *(const short8*)(xh + ki * 32 + qo);
        bufl[ki] = *(const short8*)(xl + ki * 32 + qo);
      }
    } else {
#pragma unroll
      for (int ki = 0; ki < 16; ++ki) {
        SC_LOAD(bufh[ki], xh + ki * 32 + qo);
        SC_LOAD(bufl[ki], xl + ki * 32 + qo);
      }
      WAIT8(0, bufh[0], bufh[1], bufh[2], bufh[3], bufh[4], bufh[5], bufh[6], bufh[7]);
      WAIT8(0, bufh[8], bufh[9], bufh[10], bufh[11], bufh[12], bufh[13], bufh[14], bufh[15]);
      WAIT8(0, bufl[0], bufl[1], bufl[2], bufl[3], bufl[4], bufl[5], bufl[6], bufl[7]);
      WAIT8(0, bufl[8], bufl[9], bufl[10], bufl[11], bufl[12], bufl[13], bufl[14], bufl[15]);
    }

    float4_ acc0 = {0.f, 0.f, 0.f, 0.f}, acc1 = acc0, acc2 = acc0;
#pragma unroll
    for (int ki = 0; ki < 16; ++ki) {
      const int ko = ki * 32 + qo;
      short8 b0h = *(const short8*)(wh_lds + (0 * 16 + n16) * 520 + ko);
      short8 b1h = *(const short8*)(wh_lds + (1 * 16 + n16) * 520 + ko);
      short8 b2h = *(const short8*)(wh_lds + (2 * 16 + n16) * 520 + ko);
      short8 b0l = *(const short8*)(wl_lds + (0 * 16 + n16) * 520 + ko);
      short8 b1l = *(const short8*)(wl_lds + (1 * 16 + n16) * 520 + ko);
      short8 b2l = *(const short8*)(wl_lds + (2 * 16 + n16) * 520 + ko);
      acc0 = MFMA(bufh[ki], b0h, acc0); acc0 = MFMA(bufl[ki], b0h, acc0); acc0 = MFMA(bufh[ki], b0l, acc0);
      acc1 = MFMA(bufh[ki], b1h, acc1); acc1 = MFMA(bufl[ki], b1h, acc1); acc1 = MFMA(bufh[ki], b1l, acc1);
      acc2 = MFMA(bufh[ki], b2h, acc2); acc2 = MFMA(bufl[ki], b2h, acc2); acc2 = MFMA(bufh[ki], b2l, acc2);
    }
    for (int reg = 0; reg < 4; ++reg) {
      float ar = acc0[reg], az = acc1[reg], an = acc2[reg];
      float pr = __shfl_xor(ar, 8), pz = __shfl_xor(az, 8), pn = __shfl_xor(an, 8);
      float r  = sigm(ar + pr + blds[j8]);
      float zg = sigm(az + pz + blds[8 + j8]);
      float nn = tanhf(an + blds[16 + j8] + r * (pn + blds[24 + j8]));
      float xn = (1.f - zg) * nn + zg * x_own[reg];
      x_own[reg] = xn;
      if (act) {
        size_t po = (size_t)(orow0 + reg) * 512 + col;
        u16 h, l; split2(xn, h, l);
        SC_STORE16(xpp + sw * 131072 + po, h);
        SC_STORE16(xpp + sw * 131072 + 65536 + po, l);
        float rl = fmaxf(xn, 0.f);
        u16 rh, rlo; split2(rl, rh, rlo);
        size_t so = ((size_t)(orow0 + reg) * 256 + (size_t)t) * 2048;
        outu[so + col] = rh;
        outu[so + 512 + col] = rlo;
      }
    }
    if (t < 255) grid_barrier(bar, t, 128);
  }
}

// ---------------------------------------------------------------------------
// Kernel 2: persistent LSTM chain with fused FC. 256 blocks x 512 threads.
// C==0: exact round-4 behavior. C>0 (power of 2): C-slot h ring, plain cached
// consumer loads + acquire fence every C steps (+ one before the epilogue).
// Slot layout (both modes): hpp + slot*262144 + plane*131072.
// ---------------------------------------------------------------------------
template<int C>
__global__ __launch_bounds__(512)
void lstm_fc_chain(const float* __restrict__ Wih, const float* __restrict__ Whh,
                   const float* __restrict__ bih, const float* __restrict__ bhh,
                   const float* __restrict__ fcW, const float* __restrict__ fcb,
                   u16* __restrict__ hpp, u16* outu, float* outf, u32* bar) {
  __shared__ __align__(16) u16 whh_hi[16 * 1032];
  __shared__ __align__(16) u16 whh_lo[16 * 1032];
  __shared__ __align__(16) u16 wih_hi[16 * 520];
  __shared__ __align__(16) u16 wih_lo[16 * 520];
  __shared__ float glds[128][17];
  __shared__ float pglds[2][16][4][16];
  __shared__ float bclds[16];
  __shared__ float fclds[16];

  const int tid = threadIdx.x;
  const int s = blockIdx.x;
  const int colbase = s * 4;
  const int vt = s & 63, bq = s >> 6;
  const int vbase = vt * 16;

  for (int idx = tid; idx < 16 * 1024; idx += 512) {
    int row = idx >> 10, k = idx & 1023;
    int gate = row >> 2, cc = row & 3;
    float w = Whh[(size_t)(gate * 1024 + colbase + cc) * 1024 + k];
    u16 h, l; split2(w, h, l);
    whh_hi[row * 1032 + k] = h;
    whh_lo[row * 1032 + k] = l;
  }
  for (int idx = tid; idx < 16 * 512; idx += 512) {
    int row = idx >> 9, k = idx & 511;
    int gate = row >> 2, cc = row & 3;
    float w = Wih[(size_t)(gate * 1024 + colbase + cc) * 512 + k];
    u16 h, l; split2(w, h, l);
    wih_hi[row * 520 + k] = h;
    wih_lo[row * 520 + k] = l;
  }
  if (tid < 16) {
    int gate = tid >> 2, cc = tid & 3;
    int wcol = gate * 1024 + colbase + cc;
    bclds[tid] = bih[wcol] + bhh[wcol];
    fclds[tid] = fcb[vbase + tid];
  }
  __syncthreads();

  const int lane = tid & 63, wv = tid >> 6;
  const int n16 = lane & 15, q = lane >> 4;
  const int qo = q * 8;
  const int arow = wv * 16 + n16;
  const int myrow = tid >> 2, mycol = tid & 3;
  const int fmt = wv & 1, fkq = wv >> 1;
  const int frow = bq * 32 + fmt * 16 + n16;
  const int fkbase = fkq * 256;

  short8 brh[8], brl[8];
  for (int i = 0; i < 8; ++i)
    frag_from_f32(fcW + (size_t)(vbase + n16) * 1024 + fkbase + i * 32 + qo,
                  brh[i], brl[i]);

  float c = 0.f;

  // t = 0: preacts are just biases; write h_0 into slot 0
  {
    float pi = bclds[mycol], pg = bclds[8 + mycol], po = bclds[12 + mycol];
    c = sigm(pi) * tanhf(pg);
    float h = sigm(po) * tanhf(c);
    size_t off = (size_t)myrow * 1024 + colbase + mycol;
    u16 hh, hl; split2(h, hh, hl);
    SC_STORE16(hpp + off, hh);
    SC_STORE16(hpp + 131072 + off, hl);
  }
  grid_barrier(bar, 1, 256);

  for (int t = 1; t < 256; ++t) {
    if constexpr (C > 0) {
      if ((t & (C - 1)) == 0) cache_acquire();   // kill stale ring lines
    }
    const size_t sr = (C > 0) ? (size_t)((t - 1) & (C - 1)) : (size_t)((t - 1) & 1);
    const size_t sw = (C > 0) ? (size_t)(t & (C - 1))       : (size_t)(t & 1);
    const u16* ph = hpp + sr * 262144 + (size_t)arow * 1024;
    const u16* pl = ph + 131072;
    float4_ acc = {0.f, 0.f, 0.f, 0.f};

    // recurrent part, K=1024: 4 chunks of 8 ki, double-buffered loads
    {
      short8 hb[2][8], lb[2][8];
      if constexpr (C > 0) {
#pragma unroll
        for (int j = 0; j < 8; ++j) {
          hb[0][j] = *(const short8*)(ph + j * 32 + qo);
          lb[0][j] = *(const short8*)(pl + j * 32 + qo);
        }
#pragma unroll
        for (int ch = 0; ch < 4; ++ch) {
          const int cur = ch & 1, nxt = cur ^ 1;
          if (ch < 3) {
#pragma unroll
            for (int j = 0; j < 8; ++j) {
              hb[nxt][j] = *(const short8*)(ph + ((ch + 1) * 8 + j) * 32 + qo);
              lb[nxt][j] = *(const short8*)(pl + ((ch + 1) * 8 + j) * 32 + qo);
            }
          }
#pragma unroll
          for (int j = 0; j < 8; ++j) {
            const int ko = (ch * 8 + j) * 32 + qo;
            short8 bh = *(const short8*)(whh_hi + n16 * 1032 + ko);
            short8 bl = *(const short8*)(whh_lo + n16 * 1032 + ko);
            acc = MFMA(hb[cur][j], bh, acc);
            acc = MFMA(lb[cur][j], bh, acc);
            acc = MFMA(hb[cur][j], bl, acc);
          }
        }
      } else {
#pragma unroll
        for (int j = 0; j < 8; ++j) {
          SC_LOAD(hb[0][j], ph + j * 32 + qo);
          SC_LOAD(lb[0][j], pl + j * 32 + qo);
        }
#pragma unroll
        for (int ch = 0; ch < 4; ++ch) {
          const int cur = ch & 1, nxt = cur ^ 1;
          if (ch < 3) {
#pragma unroll
            for (int j = 0; j < 8; ++j) {
              SC_LOAD(hb[nxt][j], ph + ((ch + 1) * 8 + j) * 32 + qo);
              SC_LOAD(lb[nxt][j], pl + ((ch + 1) * 8 + j) * 32 + qo);
            }
            WAIT8(16, hb[cur][0], hb[cur][1], hb[cur][2], hb[cur][3],
                      hb[cur][4], hb[cur][5], hb[cur][6], hb[cur][7]);
            WAIT8(16, lb[cur][0], lb[cur][1], lb[cur][2], lb[cur][3],
                      lb[cur][4], lb[cur][5], lb[cur][6], lb[cur][7]);
          } else {
            WAIT8(0, hb[cur][0], hb[cur][1], hb[cur][2], hb[cur][3],
                     hb[cur][4], hb[cur][5], hb[cur][6], hb[cur][7]);
            WAIT8(0, lb[cur][0], lb[cur][1], lb[cur][2], lb[cur][3],
                     lb[cur][4], lb[cur][5], lb[cur][6], lb[cur][7]);
          }
#pragma unroll
          for (int j = 0; j < 8; ++j) {
            const int ko = (ch * 8 + j) * 32 + qo;
            short8 bh = *(const short8*)(whh_hi + n16 * 1032 + ko);
            short8 bl = *(const short8*)(whh_lo + n16 * 1032 + ko);
            acc = MFMA(hb[cur][j], bh, acc);
            acc = MFMA(lb[cur][j], bh, acc);
            acc = MFMA(hb[cur][j], bl, acc);
          }
        }
      }
    }
    // input part, K=512: seq planes from outu (normal cached loads, L2-warm)
    {
      const u16* sq = outu + ((size_t)arow * 256 + t) * 2048;
      for (int ki = 0; ki < 16; ++ki) {
        const int ko = ki * 32 + qo;
        short8 sh = *(const short8*)(sq + ko);
        short8 sl = *(const short8*)(sq + 512 + ko);
        short8 bh = *(const short8*)(wih_hi + n16 * 520 + ko);
        short8 bl = *(const short8*)(wih_lo + n16 * 520 + ko);
        acc = MFMA(sh, bh, acc); acc = MFMA(sl, bh, acc); acc = MFMA(sh, bl, acc);
      }
    }
    for (int reg = 0; reg < 4; ++reg)
      glds[wv * 16 + q * 4 + reg][n16] = acc[reg];
    __syncthreads();
    {
      float pi = glds[myrow][mycol]      + bclds[mycol];
      float pf = glds[myrow][4 + mycol]  + bclds[4 + mycol];
      float pg = glds[myrow][8 + mycol]  + bclds[8 + mycol];
      float po = glds[myrow][12 + mycol] + bclds[12 + mycol];
      c = sigm(pf) * c + sigm(pi) * tanhf(pg);
      float h = sigm(po) * tanhf(c);
      size_t off = (size_t)myrow * 1024 + colbase + mycol;
      u16 hh, hl; split2(h, hh, hl);
      SC_STORE16(hpp + sw * 262144 + off, hh);
      SC_STORE16(hpp + sw * 262144 + 131072 + off, hl);
    }

    // fused FC: logits_{t-1} from h_{t-1} (slot sr)
    {
      const u16* fh = hpp + sr * 262144 + (size_t)frow * 1024 + fkbase;
      const u16* fl = fh + 131072;
      short8 fhb[8], flb[8];
      if constexpr (C > 0) {
#pragma unroll
        for (int i = 0; i < 8; ++i) {
          fhb[i] = *(const short8*)(fh + i * 32 + qo);
          flb[i] = *(const short8*)(fl + i * 32 + qo);
        }
      } else {
#pragma unroll
        for (int i = 0; i < 8; ++i) {
          SC_LOAD(fhb[i], fh + i * 32 + qo);
          SC_LOAD(flb[i], fl + i * 32 + qo);
        }
        WAIT8(0, fhb[0], fhb[1], fhb[2], fhb[3], fhb[4], fhb[5], fhb[6], fhb[7]);
        WAIT8(0, flb[0], flb[1], flb[2], flb[3], flb[4], flb[5], flb[6], flb[7]);
      }
      float4_ lacc = {0.f, 0.f, 0.f, 0.f};
#pragma unroll
      for (int i = 0; i < 8; ++i) {
        lacc = MFMA(fhb[i], brh[i], lacc);
        lacc = MFMA(flb[i], brh[i], lacc);
        lacc = MFMA(fhb[i], brl[i], lacc);
      }
      for (int reg = 0; reg < 4; ++reg)
        pglds[fmt][q * 4 + reg][fkq][n16] = lacc[reg];
      __syncthreads();
      int trow = tid >> 4, tcol = tid & 15;
      float lsum = pglds[trow >> 4][trow & 15][0][tcol] + pglds[trow >> 4][trow & 15][1][tcol] +
                   pglds[trow >> 4][trow & 15][2][tcol] + pglds[trow >> 4][trow & 15][3][tcol] +
                   fclds[tcol];
      outf[((size_t)(bq * 32 + trow) * 256 + (t - 1)) * 1024 + vbase + tcol] = lsum;
    }
    grid_barrier(bar, t + 1, 256);
  }

  // epilogue: logits_255 from h_255 (ring: slot 255&(C-1), fence first since
  // that slot's addresses were last read C steps ago; 2-slot: slot 1, sc loads)
  {
    if constexpr (C > 0) cache_acquire();
    const size_t sl = (C > 0) ? (size_t)(255 & (C - 1)) : (size_t)1;
    const u16* fh = hpp + sl * 262144 + (size_t)frow * 1024 + fkbase;
    const u16* fl = fh + 131072;
    short8 fhb[8], flb[8];
    if constexpr (C > 0) {
#pragma unroll
      for (int i = 0; i < 8; ++i) {
        fhb[i] = *(const short8*)(fh + i * 32 + qo);
        flb[i] = *(const short8*)(fl + i * 32 + qo);
      }
    } else {
#pragma unroll
      for (int i = 0; i < 8; ++i) {
        SC_LOAD(fhb[i], fh + i * 32 + qo);
        SC_LOAD(flb[i], fl + i * 32 + qo);
      }
      WAIT8(0, fhb[0], fhb[1], fhb[2], fhb[3], fhb[4], fhb[5], fhb[6], fhb[7]);
      WAIT8(0, flb[0], flb[1], flb[2], flb[3], flb[4], flb[5], flb[6], flb[7]);
    }
    float4_ lacc = {0.f, 0.f, 0.f, 0.f};
#pragma unroll
    for (int i = 0; i < 8; ++i) {
      lacc = MFMA(fhb[i], brh[i], lacc);
      lacc = MFMA(flb[i], brh[i], lacc);
      lacc = MFMA(fhb[i], brl[i], lacc);
    }
    for (int reg = 0; reg < 4; ++reg)
      pglds[fmt][q * 4 + reg][fkq][n16] = lacc[reg];
    __syncthreads();
    int trow = tid >> 4, tcol = tid & 15;
    float lsum = pglds[trow >> 4][trow & 15][0][tcol] + pglds[trow >> 4][trow & 15][1][tcol] +
                 pglds[trow >> 4][trow & 15][2][tcol] + pglds[trow >> 4][trow & 15][3][tcol] +
                 fclds[tcol];
    outf[((size_t)(bq * 32 + trow) * 256 + 255) * 1024 + vbase + tcol] = lsum;
  }
}

// ---------------------------------------------------------------------------
extern "C" void kernel_launch(void* const* d_in, const int* in_sizes, int n_in,
                              void* d_out, int out_size, void* d_ws, size_t ws_size,
                              hipStream_t stream) {
  (void)in_sizes; (void)n_in; (void)out_size;
  const float* z    = (const float*)d_in[0];
  const float* gWih = (const float*)d_in[2];
  const float* gWhh = (const float*)d_in[3];
  const float* gbih = (const float*)d_in[4];
  const float* gbhh = (const float*)d_in[5];
  const float* lWih = (const float*)d_in[6];
  const float* lWhh = (const float*)d_in[7];
  const float* lbih = (const float*)d_in[8];
  const float* lbhh = (const float*)d_in[9];
  const float* fcW  = (const float*)d_in[10];
  const float* fcb  = (const float*)d_in[11];

  const size_t XS = 262144;   // x slot bytes (2 planes x 128x512 bf16)
  const size_t HS = 524288;   // h slot bytes (2 planes x 128x1024 bf16)
  const size_t BAR = 4096;

  char* w = (char*)d_ws;
  u32* barg = (u32*)(w + 0);
  u32* barl = (u32*)(w + 256);

  hipMemsetAsync(d_ws, 0, 4096, stream);   // zero barrier counters

#define LAUNCH(CG, CL, XSLOTS)                                                     \
  do {                                                                             \
    u16* xpp = (u16*)(w + BAR);                                                    \
    u16* hpp = (u16*)(w + BAR + (size_t)(XSLOTS) * XS);                            \
    gru_chain<CG><<<128, 256, 0, stream>>>(z, gWih, gWhh, gbih, gbhh,              \
                                           (u16*)d_out, xpp, barg);                \
    lstm_fc_chain<CL><<<256, 512, 0, stream>>>(lWih, lWhh, lbih, lbhh, fcW, fcb,   \
                                               hpp, (u16*)d_out, (float*)d_out,    \
                                               barl);                              \
  } while (0)

  if      (ws_size >= BAR + 64 * XS + 128 * HS) LAUNCH(64, 128, 64);  // 83.9 MB
  else if (ws_size >= BAR + 32 * XS +  64 * HS) LAUNCH(32,  64, 32);  // 41.9 MB
  else if (ws_size >= BAR + 16 * XS +  32 * HS) LAUNCH(16,  32, 16);  // 21.0 MB
  else if (ws_size >= BAR +  8 * XS +  16 * HS) LAUNCH( 8,  16,  8);  // 10.5 MB
  else if (ws_size >= BAR +  2 * XS +   8 * HS) LAUNCH( 0,   8,  2);  //  4.7 MB (guaranteed)
  else if (ws_size >= BAR +  2 * XS +   2 * HS) LAUNCH( 0,   0,  2);  //  1.5 MB fallback
  else return;

#undef LAUNCH
}

// Round 4
// 9352.859 us; speedup vs baseline: 1.4715x; 1.1633x over previous
//
#include <hip/hip_runtime.h>
#include <stdint.h>
#include <math.h>

// Decoder: autoregressive GRU (B=128,H=512,T=256) -> LSTM (L=1024) -> FC (V=1024)
// fp32 I/O. Internal math fp32; GEMMs via MFMA 16x16x32 bf16 with split-bf16
// (hi/lo) weights AND activations, 3-pass MFMA.
//
// Round 8: round-3 counters falsified the LLC-BW theory (ring dedup bought 4%).
// New model: grid-barrier SAME-LINE ATOMIC SERIALIZATION dominates (~150cyc per
// RMW x 256 blocks ~= 16us/step lstm, x128 ~= 8us gru -- fits both kernels'
// residuals). Fix: (a) two-level tree barrier -- 16 group counter lines (128B
// apart) + root promotion, serialized RMWs 256 -> ~32; (b) split arrive/wait:
// arrive at end of step t, wait deferred past the next step's input-part GEMM
// (depends only on seq from the previous dispatch), hiding release latency and
// straggler spread under real work. Ring slot/fence invariants unchanged.

typedef unsigned short u16;
typedef unsigned int u32;
typedef __attribute__((ext_vector_type(8))) short short8;   // 8 bf16 = 4 VGPR
typedef __attribute__((ext_vector_type(4))) float float4_;  // MFMA acc

#define MFMA(a, b, c) __builtin_amdgcn_mfma_f32_16x16x32_bf16((a), (b), (c), 0, 0, 0)

// System-coherent (LLC) 16B load, bypasses L1+L2; usable only after an owning wait.
#define SC_LOAD(dst, ptr) \
  asm volatile("global_load_dwordx4 %0, %1, off sc0 sc1" : "=v"(dst) : "v"(ptr) : "memory")
// s_waitcnt that also "owns" 8 loaded regs so consumers can't be hoisted above it.
#define WAIT8(n, a0,a1,a2,a3,a4,a5,a6,a7) \
  asm volatile("s_waitcnt vmcnt(" #n ")" \
    : "+v"(a0),"+v"(a1),"+v"(a2),"+v"(a3),"+v"(a4),"+v"(a5),"+v"(a6),"+v"(a7) :: "memory")
// Coherent 2B store (write-through to LLC, complete when vmcnt retires).
#define SC_STORE16(ptr, val) \
  asm volatile("global_store_short %0, %1, off sc0 sc1" :: "v"(ptr), "v"((u32)(val)) : "memory")

__device__ __forceinline__ float bf2f(u16 u) {
  union { u32 i; float f; } v; v.i = ((u32)u) << 16; return v.f;
}
__device__ __forceinline__ u16 f2bf(float f) {
  union { float f; u32 i; } v; v.f = f;
  u32 x = v.i;
  return (u16)((x + 0x7fffu + ((x >> 16) & 1u)) >> 16);  // RNE, finite inputs only
}
__device__ __forceinline__ void split2(float w, u16& h, u16& l) {
  h = f2bf(w); l = f2bf(w - bf2f(h));
}
__device__ __forceinline__ float sigm(float x) { return 1.0f / (1.0f + expf(-x)); }

__device__ __forceinline__ void frag_from_f32(const float* p, short8& hi, short8& lo) {
  short8 h, l;
#pragma unroll
  for (int j = 0; j < 8; ++j) {
    u16 a, b; split2(p[j], a, b);
    h[j] = (short)a; l[j] = (short)b;
  }
  hi = h; lo = l;
}

// System-scope acquire: s_waitcnt + buffer_inv (invalidate-only, preserves dirty).
__device__ __forceinline__ void cache_acquire() {
  __builtin_amdgcn_fence(__ATOMIC_ACQUIRE, "");
}

// --- Two-level tree barrier -------------------------------------------------
// arrive: drain payload stores, block-sync, bump this block's GROUP counter
// (one 128B-spaced line per group); the arriver that completes the group for
// this generation promotes one atomicAdd to the ROOT line. Serialized same-line
// RMWs drop from nblk to ~(gsz + ngrp).
__device__ __forceinline__ void bar_arrive(u32* grp, u32* root, u32 gen, u32 gsz) {
  asm volatile("s_waitcnt vmcnt(0)" ::: "memory");
  __syncthreads();
  if (threadIdx.x == 0) {
    u32 old = atomicAdd(grp, 1u);
    if (old == gen * gsz - 1u) atomicAdd(root, 1u);
  }
}
// wait: spin on the root until this generation's groups have all closed.
__device__ __forceinline__ void bar_wait(u32* root, u32 gen, u32 ngrp) {
  if (threadIdx.x == 0) {
    const u32 target = gen * ngrp;
    while (__hip_atomic_load(root, __ATOMIC_RELAXED, __HIP_MEMORY_SCOPE_AGENT) < target)
      __builtin_amdgcn_s_sleep(2);
  }
  __syncthreads();
}

// ---------------------------------------------------------------------------
// Kernel 1: persistent GRU chain. 128 blocks x 256 threads. 16 groups of 8.
// C==0: 2-slot sc0sc1 mode. C>0 (power of 2): C-slot ring, plain cached
// consumer loads + acquire fence every C steps.
// Slot layout: xpp + slot*131072 + plane*65536, plane in {hi,lo}.
// ---------------------------------------------------------------------------
template<int C>
__global__ __launch_bounds__(256)
void gru_chain(const float* __restrict__ z,
               const float* __restrict__ Wih, const float* __restrict__ Whh,
               const float* __restrict__ bih, const float* __restrict__ bhh,
               u16* outu, u16* __restrict__ xpp, u32* root, u32* grpb) {
  __shared__ __align__(16) u16 wh_lds[48 * 520];
  __shared__ __align__(16) u16 wl_lds[48 * 520];
  __shared__ float blds[32];

  const int tid = threadIdx.x;
  const int wg = blockIdx.x;
  const int grp = wg & 63;
  const int mhalf = wg >> 6;
  const int jb = grp * 8;
  u32* const mygrp = grpb + (wg >> 3) * 32;   // 16 groups of 8, 128B apart

  for (int idx = tid; idx < 48 * 512; idx += 256) {
    int row = idx >> 9, k = idx & 511;
    int t3 = row >> 4, n = row & 15;
    int grow = t3 * 512 + jb + (n & 7);
    float w = ((n < 8) ? Wih : Whh)[(size_t)grow * 512 + k];
    u16 h, l; split2(w, h, l);
    wh_lds[row * 520 + k] = h;
    wl_lds[row * 520 + k] = l;
  }
  if (tid < 8) {
    blds[tid]      = bih[jb + tid] + bhh[jb + tid];
    blds[8 + tid]  = bih[512 + jb + tid] + bhh[512 + jb + tid];
    blds[16 + tid] = bih[1024 + jb + tid];
    blds[24 + tid] = bhh[1024 + jb + tid];
  }
  __syncthreads();

  const int lane = tid & 63, wv = tid >> 6;
  const int n16 = lane & 15, q = lane >> 4;
  const int j8 = n16 & 7;
  const int mrow = mhalf * 64 + wv * 16 + n16;
  const int orow0 = mhalf * 64 + wv * 16 + q * 4;
  const bool act = (n16 < 8);
  const int col = jb + j8;
  const int qo = q * 8;

  float x_own[4];

  // ---- step 1: x1 = GRU(x=0, h=z); A = z hi/lo (normal cached loads) ----
  {
    float4_ acc0 = {0.f, 0.f, 0.f, 0.f}, acc1 = acc0, acc2 = acc0;
    for (int ki = 0; ki < 16; ++ki) {
      const int ko = ki * 32 + qo;
      short8 ah, al;
      frag_from_f32(z + (size_t)mrow * 512 + ko, ah, al);
      short8 b0h = *(const short8*)(wh_lds + (0 * 16 + n16) * 520 + ko);
      short8 b1h = *(const short8*)(wh_lds + (1 * 16 + n16) * 520 + ko);
      short8 b2h = *(const short8*)(wh_lds + (2 * 16 + n16) * 520 + ko);
      short8 b0l = *(const short8*)(wl_lds + (0 * 16 + n16) * 520 + ko);
      short8 b1l = *(const short8*)(wl_lds + (1 * 16 + n16) * 520 + ko);
      short8 b2l = *(const short8*)(wl_lds + (2 * 16 + n16) * 520 + ko);
      acc0 = MFMA(ah, b0h, acc0); acc0 = MFMA(al, b0h, acc0); acc0 = MFMA(ah, b0l, acc0);
      acc1 = MFMA(ah, b1h, acc1); acc1 = MFMA(al, b1h, acc1); acc1 = MFMA(ah, b1l, acc1);
      acc2 = MFMA(ah, b2h, acc2); acc2 = MFMA(al, b2h, acc2); acc2 = MFMA(ah, b2l, acc2);
    }
    for (int reg = 0; reg < 4; ++reg) {
      float pr = __shfl_xor(acc0[reg], 8);
      float pz = __shfl_xor(acc1[reg], 8);
      float pn = __shfl_xor(acc2[reg], 8);
      float r  = sigm(pr + blds[j8]);
      float zg = sigm(pz + blds[8 + j8]);
      float nn = tanhf(blds[16 + j8] + r * (pn + blds[24 + j8]));
      float hv = act ? z[(size_t)(orow0 + reg) * 512 + col] : 0.f;
      float xn = (1.f - zg) * nn + zg * hv;
      x_own[reg] = xn;
      if (act) {
        size_t po = (size_t)(orow0 + reg) * 512 + col;
        u16 h, l; split2(xn, h, l);
        SC_STORE16(xpp + (size_t)1 * 131072 + po, h);           // slot 1 hi
        SC_STORE16(xpp + (size_t)1 * 131072 + 65536 + po, l);   // slot 1 lo
        float rl = fmaxf(xn, 0.f);
        u16 rh, rlo; split2(rl, rh, rlo);
        size_t so = ((size_t)(orow0 + reg) * 256 + 1) * 2048;
        outu[so + col] = rh;
        outu[so + 512 + col] = rlo;
      }
    }
  }
  bar_arrive(mygrp, root, 1, 8);
  bar_wait(root, 1, 16);

  // ---- steps 2..255: A = x_{t-1} hi/lo ----
  for (int t = 2; t < 256; ++t) {
    if constexpr (C > 0) {
      if ((t & (C - 1)) == 0) cache_acquire();   // kill stale ring lines
    }
    const size_t sr = (C > 0) ? (size_t)((t - 1) & (C - 1)) : (size_t)((t - 1) & 1);
    const size_t sw = (C > 0) ? (size_t)(t & (C - 1))       : (size_t)(t & 1);
    const u16* xh = xpp + sr * 131072 + (size_t)mrow * 512;
    const u16* xl = xh + 65536;
    short8 bufh[16], bufl[16];
    if constexpr (C > 0) {
#pragma unroll
      for (int ki = 0; ki < 16; ++ki) {
        bufh[ki] = *(const short8*)(xh + ki * 32 + qo);
        bufl[ki] = *(const short8*)(xl + ki * 32 + qo);
      }
    } else {
#pragma unroll
      for (int ki = 0; ki < 16; ++ki) {
        SC_LOAD(bufh[ki], xh + ki * 32 + qo);
        SC_LOAD(bufl[ki], xl + ki * 32 + qo);
      }
      WAIT8(0, bufh[0], bufh[1], bufh[2], bufh[3], bufh[4], bufh[5], bufh[6], bufh[7]);
      WAIT8(0, bufh[8], bufh[9], bufh[10], bufh[11], bufh[12], bufh[13], bufh[14], bufh[15]);
      WAIT8(0, bufl[0], bufl[1], bufl[2], bufl[3], bufl[4], bufl[5], bufl[6], bufl[7]);
      WAIT8(0, bufl[8], bufl[9], bufl[10], bufl[11], bufl[12], bufl[13], bufl[14], bufl[15]);
    }

    float4_ acc0 = {0.f, 0.f, 0.f, 0.f}, acc1 = acc0, acc2 = acc0;
#pragma unroll
    for (int ki = 0; ki < 16; ++ki) {
      const int ko = ki * 32 + qo;
      short8 b0h = *(const short8*)(wh_lds + (0 * 16 + n16) * 520 + ko);
      short8 b1h = *(const short8*)(wh_lds + (1 * 16 + n16) * 520 + ko);
      short8 b2h = *(const short8*)(wh_lds + (2 * 16 + n16) * 520 + ko);
      short8 b0l = *(const short8*)(wl_lds + (0 * 16 + n16) * 520 + ko);
      short8 b1l = *(const short8*)(wl_lds + (1 * 16 + n16) * 520 + ko);
      short8 b2l = *(const short8*)(wl_lds + (2 * 16 + n16) * 520 + ko);
      acc0 = MFMA(bufh[ki], b0h, acc0); acc0 = MFMA(bufl[ki], b0h, acc0); acc0 = MFMA(bufh[ki], b0l, acc0);
      acc1 = MFMA(bufh[ki], b1h, acc1); acc1 = MFMA(bufl[ki], b1h, acc1); acc1 = MFMA(bufh[ki], b1l, acc1);
      acc2 = MFMA(bufh[ki], b2h, acc2); acc2 = MFMA(bufl[ki], b2h, acc2); acc2 = MFMA(bufh[ki], b2l, acc2);
    }
    for (int reg = 0; reg < 4; ++reg) {
      float ar = acc0[reg], az = acc1[reg], an = acc2[reg];
      float pr = __shfl_xor(ar, 8), pz = __shfl_xor(az, 8), pn = __shfl_xor(an, 8);
      float r  = sigm(ar + pr + blds[j8]);
      float zg = sigm(az + pz + blds[8 + j8]);
      float nn = tanhf(an + blds[16 + j8] + r * (pn + blds[24 + j8]));
      float xn = (1.f - zg) * nn + zg * x_own[reg];
      x_own[reg] = xn;
      if (act) {
        size_t po = (size_t)(orow0 + reg) * 512 + col;
        u16 h, l; split2(xn, h, l);
        SC_STORE16(xpp + sw * 131072 + po, h);
        SC_STORE16(xpp + sw * 131072 + 65536 + po, l);
        float rl = fmaxf(xn, 0.f);
        u16 rh, rlo; split2(rl, rh, rlo);
        size_t so = ((size_t)(orow0 + reg) * 256 + (size_t)t) * 2048;
        outu[so + col] = rh;
        outu[so + 512 + col] = rlo;
      }
    }
    if (t < 255) { bar_arrive(mygrp, root, t, 8); bar_wait(root, t, 16); }
  }
}

// ---------------------------------------------------------------------------
// Kernel 2: persistent LSTM chain with fused FC. 256 blocks x 512 threads.
// 16 groups of 16. Split barrier: arrive at end of step t; wait deferred past
// step t+1's input-part GEMM (depends only on seq -> hides release latency).
// C==0: 2-slot sc0sc1 mode. C>0: C-slot h ring + acquire fence every C steps.
// Slot layout: hpp + slot*262144 + plane*131072.
// ---------------------------------------------------------------------------
template<int C>
__global__ __launch_bounds__(512)
void lstm_fc_chain(const float* __restrict__ Wih, const float* __restrict__ Whh,
                   const float* __restrict__ bih, const float* __restrict__ bhh,
                   const float* __restrict__ fcW, const float* __restrict__ fcb,
                   u16* __restrict__ hpp, u16* outu, float* outf,
                   u32* root, u32* grpb) {
  __shared__ __align__(16) u16 whh_hi[16 * 1032];
  __shared__ __align__(16) u16 whh_lo[16 * 1032];
  __shared__ __align__(16) u16 wih_hi[16 * 520];
  __shared__ __align__(16) u16 wih_lo[16 * 520];
  __shared__ float glds[128][17];
  __shared__ float pglds[2][16][4][16];
  __shared__ float bclds[16];
  __shared__ float fclds[16];

  const int tid = threadIdx.x;
  const int s = blockIdx.x;
  const int colbase = s * 4;
  const int vt = s & 63, bq = s >> 6;
  const int vbase = vt * 16;
  u32* const mygrp = grpb + (s >> 4) * 32;   // 16 groups of 16, 128B apart

  for (int idx = tid; idx < 16 * 1024; idx += 512) {
    int row = idx >> 10, k = idx & 1023;
    int gate = row >> 2, cc = row & 3;
    float w = Whh[(size_t)(gate * 1024 + colbase + cc) * 1024 + k];
    u16 h, l; split2(w, h, l);
    whh_hi[row * 1032 + k] = h;
    whh_lo[row * 1032 + k] = l;
  }
  for (int idx = tid; idx < 16 * 512; idx += 512) {
    int row = idx >> 9, k = idx & 511;
    int gate = row >> 2, cc = row & 3;
    float w = Wih[(size_t)(gate * 1024 + colbase + cc) * 512 + k];
    u16 h, l; split2(w, h, l);
    wih_hi[row * 520 + k] = h;
    wih_lo[row * 520 + k] = l;
  }
  if (tid < 16) {
    int gate = tid >> 2, cc = tid & 3;
    int wcol = gate * 1024 + colbase + cc;
    bclds[tid] = bih[wcol] + bhh[wcol];
    fclds[tid] = fcb[vbase + tid];
  }
  __syncthreads();

  const int lane = tid & 63, wv = tid >> 6;
  const int n16 = lane & 15, q = lane >> 4;
  const int qo = q * 8;
  const int arow = wv * 16 + n16;
  const int myrow = tid >> 2, mycol = tid & 3;
  const int fmt = wv & 1, fkq = wv >> 1;
  const int frow = bq * 32 + fmt * 16 + n16;
  const int fkbase = fkq * 256;

  short8 brh[8], brl[8];
  for (int i = 0; i < 8; ++i)
    frag_from_f32(fcW + (size_t)(vbase + n16) * 1024 + fkbase + i * 32 + qo,
                  brh[i], brl[i]);

  float c = 0.f;

  // t = 0: preacts are just biases; write h_0 into slot 0, arrive gen 1.
  {
    float pi = bclds[mycol], pg = bclds[8 + mycol], po = bclds[12 + mycol];
    c = sigm(pi) * tanhf(pg);
    float h = sigm(po) * tanhf(c);
    size_t off = (size_t)myrow * 1024 + colbase + mycol;
    u16 hh, hl; split2(h, hh, hl);
    SC_STORE16(hpp + off, hh);
    SC_STORE16(hpp + 131072 + off, hl);
  }
  bar_arrive(mygrp, root, 1, 16);

  for (int t = 1; t < 256; ++t) {
    const size_t sr = (C > 0) ? (size_t)((t - 1) & (C - 1)) : (size_t)((t - 1) & 1);
    const size_t sw = (C > 0) ? (size_t)(t & (C - 1))       : (size_t)(t & 1);
    float4_ acc = {0.f, 0.f, 0.f, 0.f};

    // ---- input part FIRST (depends only on seq, not on h): hides the wait ----
    {
      const u16* sq = outu + ((size_t)arow * 256 + t) * 2048;
      for (int ki = 0; ki < 16; ++ki) {
        const int ko = ki * 32 + qo;
        short8 sh = *(const short8*)(sq + ko);
        short8 sl = *(const short8*)(sq + 512 + ko);
        short8 bh = *(const short8*)(wih_hi + n16 * 520 + ko);
        short8 bl = *(const short8*)(wih_lo + n16 * 520 + ko);
        acc = MFMA(sh, bh, acc); acc = MFMA(sl, bh, acc); acc = MFMA(sh, bl, acc);
      }
    }

    if constexpr (C > 0) {
      if ((t & (C - 1)) == 0) cache_acquire();   // kill stale ring lines
    }
    bar_wait(root, t, 16);                       // h_{t-1} now visible

    const u16* ph = hpp + sr * 262144 + (size_t)arow * 1024;
    const u16* pl = ph + 131072;

    // recurrent part, K=1024: 4 chunks of 8 ki, double-buffered loads
    {
      short8 hb[2][8], lb[2][8];
      if constexpr (C > 0) {
#pragma unroll
        for (int j = 0; j < 8; ++j) {
          hb[0][j] = *(const short8*)(ph + j * 32 + qo);
          lb[0][j] = *(const short8*)(pl + j * 32 + qo);
        }
#pragma unroll
        for (int ch = 0; ch < 4; ++ch) {
          const int cur = ch & 1, nxt = cur ^ 1;
          if (ch < 3) {
#pragma unroll
            for (int j = 0; j < 8; ++j) {
              hb[nxt][j] = *(const short8*)(ph + ((ch + 1) * 8 + j) * 32 + qo);
              lb[nxt][j] = *(const short8*)(pl + ((ch + 1) * 8 + j) * 32 + qo);
            }
          }
#pragma unroll
          for (int j = 0; j < 8; ++j) {
            const int ko = (ch * 8 + j) * 32 + qo;
            short8 bh = *(const short8*)(whh_hi + n16 * 1032 + ko);
            short8 bl = *(const short8*)(whh_lo + n16 * 1032 + ko);
            acc = MFMA(hb[cur][j], bh, acc);
            acc = MFMA(lb[cur][j], bh, acc);
            acc = MFMA(hb[cur][j], bl, acc);
          }
        }
      } else {
#pragma unroll
        for (int j = 0; j < 8; ++j) {
          SC_LOAD(hb[0][j], ph + j * 32 + qo);
          SC_LOAD(lb[0][j], pl + j * 32 + qo);
        }
#pragma unroll
        for (int ch = 0; ch < 4; ++ch) {
          const int cur = ch & 1, nxt = cur ^ 1;
          if (ch < 3) {
#pragma unroll
            for (int j = 0; j < 8; ++j) {
              SC_LOAD(hb[nxt][j], ph + ((ch + 1) * 8 + j) * 32 + qo);
              SC_LOAD(lb[nxt][j], pl + ((ch + 1) * 8 + j) * 32 + qo);
            }
            WAIT8(16, hb[cur][0], hb[cur][1], hb[cur][2], hb[cur][3],
                      hb[cur][4], hb[cur][5], hb[cur][6], hb[cur][7]);
            WAIT8(16, lb[cur][0], lb[cur][1], lb[cur][2], lb[cur][3],
                      lb[cur][4], lb[cur][5], lb[cur][6], lb[cur][7]);
          } else {
            WAIT8(0, hb[cur][0], hb[cur][1], hb[cur][2], hb[cur][3],
                     hb[cur][4], hb[cur][5], hb[cur][6], hb[cur][7]);
            WAIT8(0, lb[cur][0], lb[cur][1], lb[cur][2], lb[cur][3],
                     lb[cur][4], lb[cur][5], lb[cur][6], lb[cur][7]);
          }
#pragma unroll
          for (int j = 0; j < 8; ++j) {
            const int ko = (ch * 8 + j) * 32 + qo;
            short8 bh = *(const short8*)(whh_hi + n16 * 1032 + ko);
            short8 bl = *(const short8*)(whh_lo + n16 * 1032 + ko);
            acc = MFMA(hb[cur][j], bh, acc);
            acc = MFMA(lb[cur][j], bh, acc);
            acc = MFMA(hb[cur][j], bl, acc);
          }
        }
      }
    }
    for (int reg = 0; reg < 4; ++reg)
      glds[wv * 16 + q * 4 + reg][n16] = acc[reg];
    __syncthreads();
    {
      float pi = glds[myrow][mycol]      + bclds[mycol];
      float pf = glds[myrow][4 + mycol]  + bclds[4 + mycol];
      float pg = glds[myrow][8 + mycol]  + bclds[8 + mycol];
      float po = glds[myrow][12 + mycol] + bclds[12 + mycol];
      c = sigm(pf) * c + sigm(pi) * tanhf(pg);
      float h = sigm(po) * tanhf(c);
      size_t off = (size_t)myrow * 1024 + colbase + mycol;
      u16 hh, hl; split2(h, hh, hl);
      SC_STORE16(hpp + sw * 262144 + off, hh);
      SC_STORE16(hpp + sw * 262144 + 131072 + off, hl);
    }

    // fused FC: logits_{t-1} from h_{t-1} (slot sr)
    {
      const u16* fh = hpp + sr * 262144 + (size_t)frow * 1024 + fkbase;
      const u16* fl = fh + 131072;
      short8 fhb[8], flb[8];
      if constexpr (C > 0) {
#pragma unroll
        for (int i = 0; i < 8; ++i) {
          fhb[i] = *(const short8*)(fh + i * 32 + qo);
          flb[i] = *(const short8*)(fl + i * 32 + qo);
        }
      } else {
#pragma unroll
        for (int i = 0; i < 8; ++i) {
          SC_LOAD(fhb[i], fh + i * 32 + qo);
          SC_LOAD(flb[i], fl + i * 32 + qo);
        }
        WAIT8(0, fhb[0], fhb[1], fhb[2], fhb[3], fhb[4], fhb[5], fhb[6], fhb[7]);
        WAIT8(0, flb[0], flb[1], flb[2], flb[3], flb[4], flb[5], flb[6], flb[7]);
      }
      float4_ lacc = {0.f, 0.f, 0.f, 0.f};
#pragma unroll
      for (int i = 0; i < 8; ++i) {
        lacc = MFMA(fhb[i], brh[i], lacc);
        lacc = MFMA(flb[i], brh[i], lacc);
        lacc = MFMA(fhb[i], brl[i], lacc);
      }
      for (int reg = 0; reg < 4; ++reg)
        pglds[fmt][q * 4 + reg][fkq][n16] = lacc[reg];
      __syncthreads();
      int trow = tid >> 4, tcol = tid & 15;
      float lsum = pglds[trow >> 4][trow & 15][0][tcol] + pglds[trow >> 4][trow & 15][1][tcol] +
                   pglds[trow >> 4][trow & 15][2][tcol] + pglds[trow >> 4][trow & 15][3][tcol] +
                   fclds[tcol];
      outf[((size_t)(bq * 32 + trow) * 256 + (t - 1)) * 1024 + vbase + tcol] = lsum;
    }
    bar_arrive(mygrp, root, (u32)t + 1, 16);   // h_t visible once gen t+1 closes
  }

  // epilogue: logits_255 from h_255 (ring: slot 255&(C-1), fence first since
  // that slot's addresses were last read C steps ago; 2-slot: slot 1, sc loads)
  {
    bar_wait(root, 256, 16);
    if constexpr (C > 0) cache_acquire();
    const size_t sl = (C > 0) ? (size_t)(255 & (C - 1)) : (size_t)1;
    const u16* fh = hpp + sl * 262144 + (size_t)frow * 1024 + fkbase;
    const u16* fl = fh + 131072;
    short8 fhb[8], flb[8];
    if constexpr (C > 0) {
#pragma unroll
      for (int i = 0; i < 8; ++i) {
        fhb[i] = *(const short8*)(fh + i * 32 + qo);
        flb[i] = *(const short8*)(fl + i * 32 + qo);
      }
    } else {
#pragma unroll
      for (int i = 0; i < 8; ++i) {
        SC_LOAD(fhb[i], fh + i * 32 + qo);
        SC_LOAD(flb[i], fl + i * 32 + qo);
      }
      WAIT8(0, fhb[0], fhb[1], fhb[2], fhb[3], fhb[4], fhb[5], fhb[6], fhb[7]);
      WAIT8(0, flb[0], flb[1], flb[2], flb[3], flb[4], flb[5], flb[6], flb[7]);
    }
    float4_ lacc = {0.f, 0.f, 0.f, 0.f};
#pragma unroll
    for (int i = 0; i < 8; ++i) {
      lacc = MFMA(fhb[i], brh[i], lacc);
      lacc = MFMA(flb[i], brh[i], lacc);
      lacc = MFMA(fhb[i], brl[i], lacc);
    }
    for (int reg = 0; reg < 4; ++reg)
      pglds[fmt][q * 4 + reg][fkq][n16] = lacc[reg];
    __syncthreads();
    int trow = tid >> 4, tcol = tid & 15;
    float lsum = pglds[trow >> 4][trow & 15][0][tcol] + pglds[trow >> 4][trow & 15][1][tcol] +
                 pglds[trow >> 4][trow & 15][2][tcol] + pglds[trow >> 4][trow & 15][3][tcol] +
                 fclds[tcol];
    outf[((size_t)(bq * 32 + trow) * 256 + 255) * 1024 + vbase + tcol] = lsum;
  }
}

// ---------------------------------------------------------------------------
extern "C" void kernel_launch(void* const* d_in, const int* in_sizes, int n_in,
                              void* d_out, int out_size, void* d_ws, size_t ws_size,
                              hipStream_t stream) {
  (void)in_sizes; (void)n_in; (void)out_size;
  const float* z    = (const float*)d_in[0];
  const float* gWih = (const float*)d_in[2];
  const float* gWhh = (const float*)d_in[3];
  const float* gbih = (const float*)d_in[4];
  const float* gbhh = (const float*)d_in[5];
  const float* lWih = (const float*)d_in[6];
  const float* lWhh = (const float*)d_in[7];
  const float* lbih = (const float*)d_in[8];
  const float* lbhh = (const float*)d_in[9];
  const float* fcW  = (const float*)d_in[10];
  const float* fcb  = (const float*)d_in[11];

  const size_t XS = 262144;   // x slot bytes (2 planes x 128x512 bf16)
  const size_t HS = 524288;   // h slot bytes (2 planes x 128x1024 bf16)
  const size_t BAR = 8192;    // barrier region: roots + 2x16 group lines

  char* w = (char*)d_ws;
  u32* rootL = (u32*)(w + 0);     // LSTM root line
  u32* rootG = (u32*)(w + 128);   // GRU root line
  u32* grpL  = (u32*)(w + 512);   // 16 x 128B LSTM group lines
  u32* grpG  = (u32*)(w + 2560);  // 16 x 128B GRU group lines

  hipMemsetAsync(d_ws, 0, BAR, stream);   // zero all barrier counters

#define LAUNCH(CG, CL, XSLOTS)                                                     \
  do {                                                                             \
    u16* xpp = (u16*)(w + BAR);                                                    \
    u16* hpp = (u16*)(w + BAR + (size_t)(XSLOTS) * XS);                            \
    gru_chain<CG><<<128, 256, 0, stream>>>(z, gWih, gWhh, gbih, gbhh,              \
                                           (u16*)d_out, xpp, rootG, grpG);         \
    lstm_fc_chain<CL><<<256, 512, 0, stream>>>(lWih, lWhh, lbih, lbhh, fcW, fcb,   \
                                               hpp, (u16*)d_out, (float*)d_out,    \
                                               rootL, grpL);                       \
  } while (0)

  if      (ws_size >= BAR + 64 * XS + 128 * HS) LAUNCH(64, 128, 64);  // 83.9 MB
  else if (ws_size >= BAR + 32 * XS +  64 * HS) LAUNCH(32,  64, 32);  // 41.9 MB
  else if (ws_size >= BAR + 16 * XS +  32 * HS) LAUNCH(16,  32, 16);  // 21.0 MB
  else if (ws_size >= BAR +  8 * XS +  16 * HS) LAUNCH( 8,  16,  8);  // 10.5 MB
  else if (ws_size >= BAR +  2 * XS +   8 * HS) LAUNCH( 0,   8,  2);  //  4.7 MB (guaranteed)
  else if (ws_size >= BAR +  2 * XS +   2 * HS) LAUNCH( 0,   0,  2);  //  1.5 MB fallback
  else return;

#undef LAUNCH
}

// Round 6
// 9066.888 us; speedup vs baseline: 1.5179x; 1.0315x over previous
//
#include <hip/hip_runtime.h>
#include <stdint.h>
#include <math.h>

// Decoder: autoregressive GRU (B=128,H=512,T=256) -> LSTM (L=1024) -> FC (V=1024)
// fp32 I/O. Internal math fp32; GEMMs via MFMA 16x16x32 bf16 with split-bf16
// (hi/lo) weights AND activations, 3-pass MFMA.
//
// Round 10: identical to round 9 (bench infra failed; clean re-measurement).
// Round 9 changes under test:
// (a) Drop the tree root: spinners poll ALL group lines with one vector load
//     (64 lanes <-> 32/16 lines, __all compare) -- removes the root-promotion
//     LLC RMW hop from every step's critical path.
// (b) Early arrive: LSTM arrives right after the h-store drain; the fused-FC
//     GEMM + outf store (which no other block consumes) moves out of the
//     cycle and overlaps other blocks' arrivals. GRU likewise arrives after
//     its x-ring stores; relu/outu seq stores overlap the wait. (C==0 2-slot
//     fallback keeps legacy order -- early arrive would race slot reuse.)
// (c) Split LSTM accumulators (input / recurrent-half0 / recurrent-half1):
//     three independent MFMA dependency chains instead of one 144-deep chain.
// Ring slot/fence invariants unchanged from rounds 7-8.

typedef unsigned short u16;
typedef unsigned int u32;
typedef __attribute__((ext_vector_type(8))) short short8;   // 8 bf16 = 4 VGPR
typedef __attribute__((ext_vector_type(4))) float float4_;  // MFMA acc

#define MFMA(a, b, c) __builtin_amdgcn_mfma_f32_16x16x32_bf16((a), (b), (c), 0, 0, 0)

// System-coherent (LLC) 16B load, bypasses L1+L2; usable only after an owning wait.
#define SC_LOAD(dst, ptr) \
  asm volatile("global_load_dwordx4 %0, %1, off sc0 sc1" : "=v"(dst) : "v"(ptr) : "memory")
// s_waitcnt that also "owns" 8 loaded regs so consumers can't be hoisted above it.
#define WAIT8(n, a0,a1,a2,a3,a4,a5,a6,a7) \
  asm volatile("s_waitcnt vmcnt(" #n ")" \
    : "+v"(a0),"+v"(a1),"+v"(a2),"+v"(a3),"+v"(a4),"+v"(a5),"+v"(a6),"+v"(a7) :: "memory")
// Coherent 2B store (write-through to LLC, complete when vmcnt retires).
#define SC_STORE16(ptr, val) \
  asm volatile("global_store_short %0, %1, off sc0 sc1" :: "v"(ptr), "v"((u32)(val)) : "memory")

__device__ __forceinline__ float bf2f(u16 u) {
  union { u32 i; float f; } v; v.i = ((u32)u) << 16; return v.f;
}
__device__ __forceinline__ u16 f2bf(float f) {
  union { float f; u32 i; } v; v.f = f;
  u32 x = v.i;
  return (u16)((x + 0x7fffu + ((x >> 16) & 1u)) >> 16);  // RNE, finite inputs only
}
__device__ __forceinline__ void split2(float w, u16& h, u16& l) {
  h = f2bf(w); l = f2bf(w - bf2f(h));
}
__device__ __forceinline__ float sigm(float x) { return 1.0f / (1.0f + expf(-x)); }

__device__ __forceinline__ void frag_from_f32(const float* p, short8& hi, short8& lo) {
  short8 h, l;
#pragma unroll
  for (int j = 0; j < 8; ++j) {
    u16 a, b; split2(p[j], a, b);
    h[j] = (short)a; l[j] = (short)b;
  }
  hi = h; lo = l;
}

// System-scope acquire: s_waitcnt + buffer_inv (invalidate-only, preserves dirty).
__device__ __forceinline__ void cache_acquire() {
  __builtin_amdgcn_fence(__ATOMIC_ACQUIRE, "");
}

// --- Flat group barrier (no root) ------------------------------------------
// arrive: drain payload stores (sc0sc1 -> LLC-visible at vmcnt retire),
// block-sync, one atomicAdd on this block's group line (128B-spaced).
__device__ __forceinline__ void bar_arrive(u32* grp) {
  asm volatile("s_waitcnt vmcnt(0)" ::: "memory");
  __syncthreads();
  if (threadIdx.x == 0) atomicAdd(grp, 1u);
}
// wait: wave 0 polls ALL NG group lines at once (lane l watches line l&(NG-1));
// done when every line reached target. Single vector load per poll iteration.
template<int NG>
__device__ __forceinline__ void bar_wait_poll(u32* grpb, u32 target) {
  if (threadIdx.x < 64) {
    u32* p = grpb + (size_t)(threadIdx.x & (NG - 1)) * 32;
    while (true) {
      u32 v = __hip_atomic_load(p, __ATOMIC_RELAXED, __HIP_MEMORY_SCOPE_AGENT);
      if (__all((int)(v >= target))) break;
      __builtin_amdgcn_s_sleep(1);
    }
  }
  __syncthreads();
}

// ---------------------------------------------------------------------------
// Kernel 1: persistent GRU chain. 128 blocks x 256 threads. 16 groups of 8.
// C==0: 2-slot sc0sc1 mode. C>0 (power of 2): C-slot ring, plain cached
// consumer loads + acquire fence every C steps.
// Slot layout: xpp + slot*131072 + plane*65536, plane in {hi,lo}.
// ---------------------------------------------------------------------------
template<int C>
__global__ __launch_bounds__(256)
void gru_chain(const float* __restrict__ z,
               const float* __restrict__ Wih, const float* __restrict__ Whh,
               const float* __restrict__ bih, const float* __restrict__ bhh,
               u16* outu, u16* __restrict__ xpp, u32* grpb) {
  __shared__ __align__(16) u16 wh_lds[48 * 520];
  __shared__ __align__(16) u16 wl_lds[48 * 520];
  __shared__ float blds[32];

  const int tid = threadIdx.x;
  const int wg = blockIdx.x;
  const int grp = wg & 63;
  const int mhalf = wg >> 6;
  const int jb = grp * 8;
  u32* const mygrp = grpb + (size_t)(wg >> 3) * 32;   // 16 groups of 8, 128B apart

  for (int idx = tid; idx < 48 * 512; idx += 256) {
    int row = idx >> 9, k = idx & 511;
    int t3 = row >> 4, n = row & 15;
    int grow = t3 * 512 + jb + (n & 7);
    float w = ((n < 8) ? Wih : Whh)[(size_t)grow * 512 + k];
    u16 h, l; split2(w, h, l);
    wh_lds[row * 520 + k] = h;
    wl_lds[row * 520 + k] = l;
  }
  if (tid < 8) {
    blds[tid]      = bih[jb + tid] + bhh[jb + tid];
    blds[8 + tid]  = bih[512 + jb + tid] + bhh[512 + jb + tid];
    blds[16 + tid] = bih[1024 + jb + tid];
    blds[24 + tid] = bhh[1024 + jb + tid];
  }
  __syncthreads();

  const int lane = tid & 63, wv = tid >> 6;
  const int n16 = lane & 15, q = lane >> 4;
  const int j8 = n16 & 7;
  const int mrow = mhalf * 64 + wv * 16 + n16;
  const int orow0 = mhalf * 64 + wv * 16 + q * 4;
  const bool act = (n16 < 8);
  const int col = jb + j8;
  const int qo = q * 8;

  float x_own[4];

  // ---- step 1: x1 = GRU(x=0, h=z); A = z hi/lo (normal cached loads) ----
  {
    float4_ acc0 = {0.f, 0.f, 0.f, 0.f}, acc1 = acc0, acc2 = acc0;
    for (int ki = 0; ki < 16; ++ki) {
      const int ko = ki * 32 + qo;
      short8 ah, al;
      frag_from_f32(z + (size_t)mrow * 512 + ko, ah, al);
      short8 b0h = *(const short8*)(wh_lds + (0 * 16 + n16) * 520 + ko);
      short8 b1h = *(const short8*)(wh_lds + (1 * 16 + n16) * 520 + ko);
      short8 b2h = *(const short8*)(wh_lds + (2 * 16 + n16) * 520 + ko);
      short8 b0l = *(const short8*)(wl_lds + (0 * 16 + n16) * 520 + ko);
      short8 b1l = *(const short8*)(wl_lds + (1 * 16 + n16) * 520 + ko);
      short8 b2l = *(const short8*)(wl_lds + (2 * 16 + n16) * 520 + ko);
      acc0 = MFMA(ah, b0h, acc0); acc0 = MFMA(al, b0h, acc0); acc0 = MFMA(ah, b0l, acc0);
      acc1 = MFMA(ah, b1h, acc1); acc1 = MFMA(al, b1h, acc1); acc1 = MFMA(ah, b1l, acc1);
      acc2 = MFMA(ah, b2h, acc2); acc2 = MFMA(al, b2h, acc2); acc2 = MFMA(ah, b2l, acc2);
    }
    for (int reg = 0; reg < 4; ++reg) {
      float pr = __shfl_xor(acc0[reg], 8);
      float pz = __shfl_xor(acc1[reg], 8);
      float pn = __shfl_xor(acc2[reg], 8);
      float r  = sigm(pr + blds[j8]);
      float zg = sigm(pz + blds[8 + j8]);
      float nn = tanhf(blds[16 + j8] + r * (pn + blds[24 + j8]));
      float hv = act ? z[(size_t)(orow0 + reg) * 512 + col] : 0.f;
      float xn = (1.f - zg) * nn + zg * hv;
      x_own[reg] = xn;
      if (act) {
        size_t po = (size_t)(orow0 + reg) * 512 + col;
        u16 h, l; split2(xn, h, l);
        SC_STORE16(xpp + (size_t)1 * 131072 + po, h);           // slot 1 hi
        SC_STORE16(xpp + (size_t)1 * 131072 + 65536 + po, l);   // slot 1 lo
      }
    }
  }
  bar_arrive(mygrp);                          // gen 1
  if (act) {                                  // seq stores overlap the wait
    for (int reg = 0; reg < 4; ++reg) {
      float rl = fmaxf(x_own[reg], 0.f);
      u16 rh, rlo; split2(rl, rh, rlo);
      size_t so = ((size_t)(orow0 + reg) * 256 + 1) * 2048;
      outu[so + col] = rh;
      outu[so + 512 + col] = rlo;
    }
  }
  bar_wait_poll<16>(grpb, 8u);

  // ---- steps 2..255: A = x_{t-1} hi/lo ----
  for (int t = 2; t < 256; ++t) {
    if constexpr (C > 0) {
      if ((t & (C - 1)) == 0) cache_acquire();   // kill stale ring lines
    }
    const size_t sr = (C > 0) ? (size_t)((t - 1) & (C - 1)) : (size_t)((t - 1) & 1);
    const size_t sw = (C > 0) ? (size_t)(t & (C - 1))       : (size_t)(t & 1);
    const u16* xh = xpp + sr * 131072 + (size_t)mrow * 512;
    const u16* xl = xh + 65536;
    short8 bufh[16], bufl[16];
    if constexpr (C > 0) {
#pragma unroll
      for (int ki = 0; ki < 16; ++ki) {
        bufh[ki] = *(const short8*)(xh + ki * 32 + qo);
        bufl[ki] = *(const short8*)(xl + ki * 32 + qo);
      }
    } else {
#pragma unroll
      for (int ki = 0; ki < 16; ++ki) {
        SC_LOAD(bufh[ki], xh + ki * 32 + qo);
        SC_LOAD(bufl[ki], xl + ki * 32 + qo);
      }
      WAIT8(0, bufh[0], bufh[1], bufh[2], bufh[3], bufh[4], bufh[5], bufh[6], bufh[7]);
      WAIT8(0, bufh[8], bufh[9], bufh[10], bufh[11], bufh[12], bufh[13], bufh[14], bufh[15]);
      WAIT8(0, bufl[0], bufl[1], bufl[2], bufl[3], bufl[4], bufl[5], bufl[6], bufl[7]);
      WAIT8(0, bufl[8], bufl[9], bufl[10], bufl[11], bufl[12], bufl[13], bufl[14], bufl[15]);
    }

    float4_ acc0 = {0.f, 0.f, 0.f, 0.f}, acc1 = acc0, acc2 = acc0;
#pragma unroll
    for (int ki = 0; ki < 16; ++ki) {
      const int ko = ki * 32 + qo;
      short8 b0h = *(const short8*)(wh_lds + (0 * 16 + n16) * 520 + ko);
      short8 b1h = *(const short8*)(wh_lds + (1 * 16 + n16) * 520 + ko);
      short8 b2h = *(const short8*)(wh_lds + (2 * 16 + n16) * 520 + ko);
      short8 b0l = *(const short8*)(wl_lds + (0 * 16 + n16) * 520 + ko);
      short8 b1l = *(const short8*)(wl_lds + (1 * 16 + n16) * 520 + ko);
      short8 b2l = *(const short8*)(wl_lds + (2 * 16 + n16) * 520 + ko);
      acc0 = MFMA(bufh[ki], b0h, acc0); acc0 = MFMA(bufl[ki], b0h, acc0); acc0 = MFMA(bufh[ki], b0l, acc0);
      acc1 = MFMA(bufh[ki], b1h, acc1); acc1 = MFMA(bufl[ki], b1h, acc1); acc1 = MFMA(bufh[ki], b1l, acc1);
      acc2 = MFMA(bufh[ki], b2h, acc2); acc2 = MFMA(bufl[ki], b2h, acc2); acc2 = MFMA(bufh[ki], b2l, acc2);
    }
    // compute x_t and store the ring FIRST (the only data other blocks need)
    for (int reg = 0; reg < 4; ++reg) {
      float ar = acc0[reg], az = acc1[reg], an = acc2[reg];
      float pr = __shfl_xor(ar, 8), pz = __shfl_xor(az, 8), pn = __shfl_xor(an, 8);
      float r  = sigm(ar + pr + blds[j8]);
      float zg = sigm(az + pz + blds[8 + j8]);
      float nn = tanhf(an + blds[16 + j8] + r * (pn + blds[24 + j8]));
      float xn = (1.f - zg) * nn + zg * x_own[reg];
      x_own[reg] = xn;
      if (act) {
        size_t po = (size_t)(orow0 + reg) * 512 + col;
        u16 h, l; split2(xn, h, l);
        SC_STORE16(xpp + sw * 131072 + po, h);
        SC_STORE16(xpp + sw * 131072 + 65536 + po, l);
      }
    }
    if (t < 255) bar_arrive(mygrp);           // gen t
    if (act) {                                // seq stores overlap the wait
      for (int reg = 0; reg < 4; ++reg) {
        float rl = fmaxf(x_own[reg], 0.f);
        u16 rh, rlo; split2(rl, rh, rlo);
        size_t so = ((size_t)(orow0 + reg) * 256 + (size_t)t) * 2048;
        outu[so + col] = rh;
        outu[so + 512 + col] = rlo;
      }
    }
    if (t < 255) bar_wait_poll<16>(grpb, (u32)t * 8u);
  }
}

// ---------------------------------------------------------------------------
// Kernel 2: persistent LSTM chain with fused FC. 256 blocks x 512 threads.
// 32 groups of 8. Early arrive (ring mode): arrive right after h-store drain;
// FC runs outside the inter-block cycle. Wait deferred past the next step's
// input-part GEMM. C==0 2-slot fallback keeps the legacy arrive-after-FC
// order (early arrive would race 2-slot reuse).
// Slot layout: hpp + slot*262144 + plane*131072.
// ---------------------------------------------------------------------------
template<int C>
__global__ __launch_bounds__(512)
void lstm_fc_chain(const float* __restrict__ Wih, const float* __restrict__ Whh,
                   const float* __restrict__ bih, const float* __restrict__ bhh,
                   const float* __restrict__ fcW, const float* __restrict__ fcb,
                   u16* __restrict__ hpp, u16* outu, float* outf, u32* grpb) {
  __shared__ __align__(16) u16 whh_hi[16 * 1032];
  __shared__ __align__(16) u16 whh_lo[16 * 1032];
  __shared__ __align__(16) u16 wih_hi[16 * 520];
  __shared__ __align__(16) u16 wih_lo[16 * 520];
  __shared__ float glds[128][17];
  __shared__ float pglds[2][16][4][16];
  __shared__ float bclds[16];
  __shared__ float fclds[16];

  const int tid = threadIdx.x;
  const int s = blockIdx.x;
  const int colbase = s * 4;
  const int vt = s & 63, bq = s >> 6;
  const int vbase = vt * 16;
  u32* const mygrp = grpb + (size_t)(s >> 3) * 32;   // 32 groups of 8, 128B apart

  for (int idx = tid; idx < 16 * 1024; idx += 512) {
    int row = idx >> 10, k = idx & 1023;
    int gate = row >> 2, cc = row & 3;
    float w = Whh[(size_t)(gate * 1024 + colbase + cc) * 1024 + k];
    u16 h, l; split2(w, h, l);
    whh_hi[row * 1032 + k] = h;
    whh_lo[row * 1032 + k] = l;
  }
  for (int idx = tid; idx < 16 * 512; idx += 512) {
    int row = idx >> 9, k = idx & 511;
    int gate = row >> 2, cc = row & 3;
    float w = Wih[(size_t)(gate * 1024 + colbase + cc) * 512 + k];
    u16 h, l; split2(w, h, l);
    wih_hi[row * 520 + k] = h;
    wih_lo[row * 520 + k] = l;
  }
  if (tid < 16) {
    int gate = tid >> 2, cc = tid & 3;
    int wcol = gate * 1024 + colbase + cc;
    bclds[tid] = bih[wcol] + bhh[wcol];
    fclds[tid] = fcb[vbase + tid];
  }
  __syncthreads();

  const int lane = tid & 63, wv = tid >> 6;
  const int n16 = lane & 15, q = lane >> 4;
  const int qo = q * 8;
  const int arow = wv * 16 + n16;
  const int myrow = tid >> 2, mycol = tid & 3;
  const int fmt = wv & 1, fkq = wv >> 1;
  const int frow = bq * 32 + fmt * 16 + n16;
  const int fkbase = fkq * 256;

  short8 brh[8], brl[8];
  for (int i = 0; i < 8; ++i)
    frag_from_f32(fcW + (size_t)(vbase + n16) * 1024 + fkbase + i * 32 + qo,
                  brh[i], brl[i]);

  float c = 0.f;

  // t = 0: preacts are just biases; write h_0 into slot 0, arrive gen 1.
  {
    float pi = bclds[mycol], pg = bclds[8 + mycol], po = bclds[12 + mycol];
    c = sigm(pi) * tanhf(pg);
    float h = sigm(po) * tanhf(c);
    size_t off = (size_t)myrow * 1024 + colbase + mycol;
    u16 hh, hl; split2(h, hh, hl);
    SC_STORE16(hpp + off, hh);
    SC_STORE16(hpp + 131072 + off, hl);
  }
  bar_arrive(mygrp);   // gen 1

  for (int t = 1; t < 256; ++t) {
    const size_t sr = (C > 0) ? (size_t)((t - 1) & (C - 1)) : (size_t)((t - 1) & 1);
    const size_t sw = (C > 0) ? (size_t)(t & (C - 1))       : (size_t)(t & 1);

    // ---- input part FIRST (depends only on seq, not on h): hides the wait ----
    float4_ accI = {0.f, 0.f, 0.f, 0.f};
    {
      const u16* sq = outu + ((size_t)arow * 256 + t) * 2048;
      for (int ki = 0; ki < 16; ++ki) {
        const int ko = ki * 32 + qo;
        short8 sh = *(const short8*)(sq + ko);
        short8 sl = *(const short8*)(sq + 512 + ko);
        short8 bh = *(const short8*)(wih_hi + n16 * 520 + ko);
        short8 bl = *(const short8*)(wih_lo + n16 * 520 + ko);
        accI = MFMA(sh, bh, accI); accI = MFMA(sl, bh, accI); accI = MFMA(sh, bl, accI);
      }
    }

    if constexpr (C > 0) {
      if ((t & (C - 1)) == 0) cache_acquire();   // kill stale ring lines
    }
    bar_wait_poll<32>(grpb, (u32)t * 8u);        // h_{t-1} now visible

    const u16* ph = hpp + sr * 262144 + (size_t)arow * 1024;
    const u16* pl = ph + 131072;

    // recurrent part, K=1024: 4 chunks of 8 ki; two independent acc chains
    float4_ accR0 = {0.f, 0.f, 0.f, 0.f}, accR1 = accR0;
    {
      short8 hb[2][8], lb[2][8];
      if constexpr (C > 0) {
#pragma unroll
        for (int j = 0; j < 8; ++j) {
          hb[0][j] = *(const short8*)(ph + j * 32 + qo);
          lb[0][j] = *(const short8*)(pl + j * 32 + qo);
        }
#pragma unroll
        for (int ch = 0; ch < 4; ++ch) {
          const int cur = ch & 1, nxt = cur ^ 1;
          if (ch < 3) {
#pragma unroll
            for (int j = 0; j < 8; ++j) {
              hb[nxt][j] = *(const short8*)(ph + ((ch + 1) * 8 + j) * 32 + qo);
              lb[nxt][j] = *(const short8*)(pl + ((ch + 1) * 8 + j) * 32 + qo);
            }
          }
          float4_& accR = (ch < 2) ? accR0 : accR1;
#pragma unroll
          for (int j = 0; j < 8; ++j) {
            const int ko = (ch * 8 + j) * 32 + qo;
            short8 bh = *(const short8*)(whh_hi + n16 * 1032 + ko);
            short8 bl = *(const short8*)(whh_lo + n16 * 1032 + ko);
            accR = MFMA(hb[cur][j], bh, accR);
            accR = MFMA(lb[cur][j], bh, accR);
            accR = MFMA(hb[cur][j], bl, accR);
          }
        }
      } else {
#pragma unroll
        for (int j = 0; j < 8; ++j) {
          SC_LOAD(hb[0][j], ph + j * 32 + qo);
          SC_LOAD(lb[0][j], pl + j * 32 + qo);
        }
#pragma unroll
        for (int ch = 0; ch < 4; ++ch) {
          const int cur = ch & 1, nxt = cur ^ 1;
          if (ch < 3) {
#pragma unroll
            for (int j = 0; j < 8; ++j) {
              SC_LOAD(hb[nxt][j], ph + ((ch + 1) * 8 + j) * 32 + qo);
              SC_LOAD(lb[nxt][j], pl + ((ch + 1) * 8 + j) * 32 + qo);
            }
            WAIT8(16, hb[cur][0], hb[cur][1], hb[cur][2], hb[cur][3],
                      hb[cur][4], hb[cur][5], hb[cur][6], hb[cur][7]);
            WAIT8(16, lb[cur][0], lb[cur][1], lb[cur][2], lb[cur][3],
                      lb[cur][4], lb[cur][5], lb[cur][6], lb[cur][7]);
          } else {
            WAIT8(0, hb[cur][0], hb[cur][1], hb[cur][2], hb[cur][3],
                     hb[cur][4], hb[cur][5], hb[cur][6], hb[cur][7]);
            WAIT8(0, lb[cur][0], lb[cur][1], lb[cur][2], lb[cur][3],
                     lb[cur][4], lb[cur][5], lb[cur][6], lb[cur][7]);
          }
          float4_& accR = (ch < 2) ? accR0 : accR1;
#pragma unroll
          for (int j = 0; j < 8; ++j) {
            const int ko = (ch * 8 + j) * 32 + qo;
            short8 bh = *(const short8*)(whh_hi + n16 * 1032 + ko);
            short8 bl = *(const short8*)(whh_lo + n16 * 1032 + ko);
            accR = MFMA(hb[cur][j], bh, accR);
            accR = MFMA(lb[cur][j], bh, accR);
            accR = MFMA(hb[cur][j], bl, accR);
          }
        }
      }
    }
    for (int reg = 0; reg < 4; ++reg)
      glds[wv * 16 + q * 4 + reg][n16] = accI[reg] + accR0[reg] + accR1[reg];
    __syncthreads();
    {
      float pi = glds[myrow][mycol]      + bclds[mycol];
      float pf = glds[myrow][4 + mycol]  + bclds[4 + mycol];
      float pg = glds[myrow][8 + mycol]  + bclds[8 + mycol];
      float po = glds[myrow][12 + mycol] + bclds[12 + mycol];
      c = sigm(pf) * c + sigm(pi) * tanhf(pg);
      float h = sigm(po) * tanhf(c);
      size_t off = (size_t)myrow * 1024 + colbase + mycol;
      u16 hh, hl; split2(h, hh, hl);
      SC_STORE16(hpp + sw * 262144 + off, hh);
      SC_STORE16(hpp + sw * 262144 + 131072 + off, hl);
    }

    // ring mode: arrive NOW -- the FC below is not consumed by other blocks.
    // Slot sr is not rewritten for >= C-1 >= 7 generations, so FC's cached
    // reads below cannot race slot reuse.
    if constexpr (C > 0) bar_arrive(mygrp);   // gen t+1

    // fused FC: logits_{t-1} from h_{t-1} (slot sr)
    {
      const u16* fh = hpp + sr * 262144 + (size_t)frow * 1024 + fkbase;
      const u16* fl = fh + 131072;
      short8 fhb[8], flb[8];
      if constexpr (C > 0) {
#pragma unroll
        for (int i = 0; i < 8; ++i) {
          fhb[i] = *(const short8*)(fh + i * 32 + qo);
          flb[i] = *(const short8*)(fl + i * 32 + qo);
        }
      } else {
#pragma unroll
        for (int i = 0; i < 8; ++i) {
          SC_LOAD(fhb[i], fh + i * 32 + qo);
          SC_LOAD(flb[i], fl + i * 32 + qo);
        }
        WAIT8(0, fhb[0], fhb[1], fhb[2], fhb[3], fhb[4], fhb[5], fhb[6], fhb[7]);
        WAIT8(0, flb[0], flb[1], flb[2], flb[3], flb[4], flb[5], flb[6], flb[7]);
      }
      float4_ lacc = {0.f, 0.f, 0.f, 0.f};
#pragma unroll
      for (int i = 0; i < 8; ++i) {
        lacc = MFMA(fhb[i], brh[i], lacc);
        lacc = MFMA(flb[i], brh[i], lacc);
        lacc = MFMA(fhb[i], brl[i], lacc);
      }
      for (int reg = 0; reg < 4; ++reg)
        pglds[fmt][q * 4 + reg][fkq][n16] = lacc[reg];
      __syncthreads();
      int trow = tid >> 4, tcol = tid & 15;
      float lsum = pglds[trow >> 4][trow & 15][0][tcol] + pglds[trow >> 4][trow & 15][1][tcol] +
                   pglds[trow >> 4][trow & 15][2][tcol] + pglds[trow >> 4][trow & 15][3][tcol] +
                   fclds[tcol];
      outf[((size_t)(bq * 32 + trow) * 256 + (t - 1)) * 1024 + vbase + tcol] = lsum;
    }

    if constexpr (C == 0) bar_arrive(mygrp);  // legacy order for 2-slot mode
  }

  // epilogue: logits_255 from h_255 (ring: slot 255&(C-1), fence first since
  // that slot's addresses were last read C steps ago; 2-slot: slot 1, sc loads)
  {
    bar_wait_poll<32>(grpb, 256u * 8u);
    if constexpr (C > 0) cache_acquire();
    const size_t sl = (C > 0) ? (size_t)(255 & (C - 1)) : (size_t)1;
    const u16* fh = hpp + sl * 262144 + (size_t)frow * 1024 + fkbase;
    const u16* fl = fh + 131072;
    short8 fhb[8], flb[8];
    if constexpr (C > 0) {
#pragma unroll
      for (int i = 0; i < 8; ++i) {
        fhb[i] = *(const short8*)(fh + i * 32 + qo);
        flb[i] = *(const short8*)(fl + i * 32 + qo);
      }
    } else {
#pragma unroll
      for (int i = 0; i < 8; ++i) {
        SC_LOAD(fhb[i], fh + i * 32 + qo);
        SC_LOAD(flb[i], fl + i * 32 + qo);
      }
      WAIT8(0, fhb[0], fhb[1], fhb[2], fhb[3], fhb[4], fhb[5], fhb[6], fhb[7]);
      WAIT8(0, flb[0], flb[1], flb[2], flb[3], flb[4], flb[5], flb[6], flb[7]);
    }
    float4_ lacc = {0.f, 0.f, 0.f, 0.f};
#pragma unroll
    for (int i = 0; i < 8; ++i) {
      lacc = MFMA(fhb[i], brh[i], lacc);
      lacc = MFMA(flb[i], brh[i], lacc);
      lacc = MFMA(fhb[i], brl[i], lacc);
    }
    for (int reg = 0; reg < 4; ++reg)
      pglds[fmt][q * 4 + reg][fkq][n16] = lacc[reg];
    __syncthreads();
    int trow = tid >> 4, tcol = tid & 15;
    float lsum = pglds[trow >> 4][trow & 15][0][tcol] + pglds[trow >> 4][trow & 15][1][tcol] +
                 pglds[trow >> 4][trow & 15][2][tcol] + pglds[trow >> 4][trow & 15][3][tcol] +
                 fclds[tcol];
    outf[((size_t)(bq * 32 + trow) * 256 + 255) * 1024 + vbase + tcol] = lsum;
  }
}

// ---------------------------------------------------------------------------
extern "C" void kernel_launch(void* const* d_in, const int* in_sizes, int n_in,
                              void* d_out, int out_size, void* d_ws, size_t ws_size,
                              hipStream_t stream) {
  (void)in_sizes; (void)n_in; (void)out_size;
  const float* z    = (const float*)d_in[0];
  const float* gWih = (const float*)d_in[2];
  const float* gWhh = (const float*)d_in[3];
  const float* gbih = (const float*)d_in[4];
  const float* gbhh = (const float*)d_in[5];
  const float* lWih = (const float*)d_in[6];
  const float* lWhh = (const float*)d_in[7];
  const float* lbih = (const float*)d_in[8];
  const float* lbhh = (const float*)d_in[9];
  const float* fcW  = (const float*)d_in[10];
  const float* fcb  = (const float*)d_in[11];

  const size_t XS = 262144;   // x slot bytes (2 planes x 128x512 bf16)
  const size_t HS = 524288;   // h slot bytes (2 planes x 128x1024 bf16)
  const size_t BAR = 8192;    // barrier region: 32 LSTM + 16 GRU group lines

  char* w = (char*)d_ws;
  u32* grpL = (u32*)(w + 512);    // 32 x 128B LSTM group lines
  u32* grpG = (u32*)(w + 4608);   // 16 x 128B GRU group lines

  hipMemsetAsync(d_ws, 0, BAR, stream);   // zero all barrier counters

#define LAUNCH(CG, CL, XSLOTS)                                                     \
  do {                                                                             \
    u16* xpp = (u16*)(w + BAR);                                                    \
    u16* hpp = (u16*)(w + BAR + (size_t)(XSLOTS) * XS);                            \
    gru_chain<CG><<<128, 256, 0, stream>>>(z, gWih, gWhh, gbih, gbhh,              \
                                           (u16*)d_out, xpp, grpG);                \
    lstm_fc_chain<CL><<<256, 512, 0, stream>>>(lWih, lWhh, lbih, lbhh, fcW, fcb,   \
                                               hpp, (u16*)d_out, (float*)d_out,    \
                                               grpL);                              \
  } while (0)

  if      (ws_size >= BAR + 64 * XS + 128 * HS) LAUNCH(64, 128, 64);  // 83.9 MB
  else if (ws_size >= BAR + 32 * XS +  64 * HS) LAUNCH(32,  64, 32);  // 41.9 MB
  else if (ws_size >= BAR + 16 * XS +  32 * HS) LAUNCH(16,  32, 16);  // 21.0 MB
  else if (ws_size >= BAR +  8 * XS +  16 * HS) LAUNCH( 8,  16,  8);  // 10.5 MB
  else if (ws_size >= BAR +  2 * XS +   8 * HS) LAUNCH( 0,   8,  2);  //  4.7 MB (guaranteed)
  else if (ws_size >= BAR +  2 * XS +   2 * HS) LAUNCH( 0,   0,  2);  //  1.5 MB fallback
  else return;

#undef LAUNCH
}